// Round 11
// baseline (436.258 us; speedup 1.0000x reference)
//
#include <hip/hip_runtime.h>

// Problem constants (B=1)
constexpr int Cc = 32;
constexpr int Dd = 48;
constexpr int Hh = 96;
constexpr int Ww = 192;
constexpr int TW = 16;           // W-kernel tile width
constexpr int NT = Ww / TW;      // 12 tiles
constexpr float NEGBIG = -3.402823466e+38f;

// ---- DPP helpers ------------------------------------------------------------
// NOTE: must use __builtin_amdgcn_update_dpp (not inline asm) — the compiler's
// hazard recognizer inserts the required VALU->DPP wait states only for
// compiler-known DPP ops. Inline-asm DPP caused silent corruption (round 3).
template <int CTRL, int RM>
__device__ __forceinline__ float dppmov(float v) {
    int i = __builtin_bit_cast(int, v);
    int r = __builtin_amdgcn_update_dpp(i, i, CTRL, RM, 0xF, false);
    return __builtin_bit_cast(float, r);
}

__device__ __forceinline__ float rdlane(float v, int idx) {
    int r = __builtin_amdgcn_readlane(__builtin_bit_cast(int, v), idx);
    return __builtin_bit_cast(float, r);
}

__device__ __forceinline__ unsigned f2h(float v) {
    return (unsigned)__builtin_bit_cast(unsigned short, (_Float16)v);
}
__device__ __forceinline__ float h2f(unsigned short u) {
    return (float)__builtin_bit_cast(_Float16, u);
}

// Max over lanes 0..47, broadcast. Row-confined: junk in lanes 48..63 never
// enters the reduction.
__device__ __forceinline__ float wave_max48(float v) {
    v = fmaxf(v, dppmov<0x111, 0xF>(v));   // row_shr:1
    v = fmaxf(v, dppmov<0x112, 0xF>(v));   // row_shr:2
    v = fmaxf(v, dppmov<0x114, 0xF>(v));   // row_shr:4
    v = fmaxf(v, dppmov<0x118, 0xF>(v));   // row_shr:8
    v = fmaxf(v, dppmov<0x142, 0x2>(v));   // row_bcast:15 -> row1: lane31=max(0..31)
    v = fmaxf(v, dppmov<0x143, 0x4>(v));   // row_bcast:31 -> row2: lane47=max(0..47)
    return rdlane(v, 47);
}

// One SGA step (lane = d). Lanes >= 48 compute garbage that never propagates
// back into lanes 0..47.
__device__ __forceinline__ float sga_step(float A, float cs, float g0v, float g1v, float g2v,
                                          float g3v, float g4v, bool is47, bool first) {
    float dm1 = dppmov<0x138, 0xF>(A);             // wave_shr:1, lane0 keeps own
    float dp1 = dppmov<0x130, 0xF>(A);             // wave_shl:1
    dp1 = is47 ? A : dp1;                          // d+1 clamp at d=47
    float mx = wave_max48(A);
    float r = g0v * cs + g1v * A + g2v * dm1 + g3v * dp1 + g4v * mx;
    return first ? cs : r;
}

// ============================================================================
// W-pair kernel (proven, rounds 6-10, ~100-103 us): fwd scan (ga) stashes a0
// fp16 on-chip (LDS tiles 0-7, static reg banks 8-11), rev scan (gb)
// combines, writes out = max(a0,a1) once. 1 wave/block, no barriers.
// ============================================================================
__global__ __launch_bounds__(64, 4) void sga_w4(const float* __restrict__ x,
                                                const float* __restrict__ ga,
                                                const float* __restrict__ gb,
                                                float* __restrict__ out) {
    __shared__ unsigned sstash[64][Dd];   // tiles 0..7, [t*8+r][lane]
    __shared__ float xo[Dd][TW + 1];      // x tile / flush tile

    const int bid = blockIdx.x;
    const int c = bid / Hh;
    const int h = bid - c * Hh;
    const int lane = threadIdx.x;
    const size_t HW = (size_t)Hh * Ww;

    const float* xrow = x + (size_t)c * Dd * HW + (size_t)h * Ww;
    const float* garow = ga + (size_t)c * 5 * HW + (size_t)h * Ww;
    const float* gbrow = gb + (size_t)c * 5 * HW + (size_t)h * Ww;
    float* orow = out + (size_t)c * Dd * HW + (size_t)h * Ww;

    const int dl = (lane < Dd) ? lane : (Dd - 1);
    const bool is47 = (lane == Dd - 1);

    int srow[3], scol[3];
#pragma unroll
    for (int i = 0; i < 3; ++i) {
        const int e4 = lane + i * 64;
        srow[i] = e4 >> 2;
        scol[i] = (e4 & 3) * 4;
    }
    const int gk = lane >> 4;
    const int gwi = lane & 15;

    float4 pre[3];
    float gA, g4r, gAn = 0.f, g4n = 0.f;
    unsigned tr[8];
    unsigned sv0[8], sv1[8], sv2[8], sv3[8];

    {
#pragma unroll
        for (int i = 0; i < 3; ++i)
            pre[i] = *reinterpret_cast<const float4*>(xrow + (size_t)srow[i] * HW + scol[i]);
        gA = garow[(size_t)gk * HW + gwi];
        g4r = garow[(size_t)4 * HW + gwi];
#pragma unroll
        for (int i = 0; i < 3; ++i) {
            xo[srow[i]][scol[i] + 0] = pre[i].x;
            xo[srow[i]][scol[i] + 1] = pre[i].y;
            xo[srow[i]][scol[i] + 2] = pre[i].z;
            xo[srow[i]][scol[i] + 3] = pre[i].w;
        }
    }

    float A = NEGBIG;

    // forward: a0 -> on-chip fp16 stash
    for (int t = 0; t < NT; ++t) {
        if (t + 1 < NT) {
            const int wn = (t + 1) * TW;
#pragma unroll
            for (int i = 0; i < 3; ++i)
                pre[i] = *reinterpret_cast<const float4*>(xrow + (size_t)srow[i] * HW + wn + scol[i]);
            gAn = garow[(size_t)gk * HW + wn + gwi];
            g4n = garow[(size_t)4 * HW + wn + gwi];
        }
#pragma unroll
        for (int wk = 0; wk < TW; ++wk) {
            const float g0v = rdlane(gA, wk);
            const float g1v = rdlane(gA, 16 + wk);
            const float g2v = rdlane(gA, 32 + wk);
            const float g3v = rdlane(gA, 48 + wk);
            const float g4v = rdlane(g4r, wk);
            const float cs = xo[dl][wk];
            A = sga_step(A, cs, g0v, g1v, g2v, g3v, g4v, is47, (t == 0 && wk == 0));
            const unsigned hu = f2h(A);
            if ((wk & 1) == 0) tr[wk >> 1] = hu;
            else tr[wk >> 1] |= hu << 16;
        }
        if (t < 8) {
            if (lane < Dd) {
#pragma unroll
                for (int r = 0; r < 8; ++r) sstash[t * 8 + r][lane] = tr[r];
            }
        } else if (t == 8) {
#pragma unroll
            for (int r = 0; r < 8; ++r) sv0[r] = tr[r];
        } else if (t == 9) {
#pragma unroll
            for (int r = 0; r < 8; ++r) sv1[r] = tr[r];
        } else if (t == 10) {
#pragma unroll
            for (int r = 0; r < 8; ++r) sv2[r] = tr[r];
        } else {
#pragma unroll
            for (int r = 0; r < 8; ++r) sv3[r] = tr[r];
        }
        if (t + 1 < NT) {
#pragma unroll
            for (int i = 0; i < 3; ++i) {
                xo[srow[i]][scol[i] + 0] = pre[i].x;
                xo[srow[i]][scol[i] + 1] = pre[i].y;
                xo[srow[i]][scol[i] + 2] = pre[i].z;
                xo[srow[i]][scol[i] + 3] = pre[i].w;
            }
            gA = gAn;
            g4r = g4n;
        }
    }

    // reverse + combine + single write
    A = NEGBIG;
    {
        const int w0 = (NT - 1) * TW;
        gA = gbrow[(size_t)gk * HW + w0 + gwi];
        g4r = gbrow[(size_t)4 * HW + w0 + gwi];
    }
    for (int t = NT - 1; t >= 0; --t) {
        const int w0 = t * TW;
        if (t > 0) {
            const int wn = w0 - TW;
#pragma unroll
            for (int i = 0; i < 3; ++i)
                pre[i] = *reinterpret_cast<const float4*>(xrow + (size_t)srow[i] * HW + wn + scol[i]);
            gAn = gbrow[(size_t)gk * HW + wn + gwi];
            g4n = gbrow[(size_t)4 * HW + wn + gwi];
        }
        unsigned rr[8];
        if (t < 8) {
#pragma unroll
            for (int r = 0; r < 8; ++r) rr[r] = sstash[t * 8 + r][dl];
        } else if (t == 8) {
#pragma unroll
            for (int r = 0; r < 8; ++r) rr[r] = sv0[r];
        } else if (t == 9) {
#pragma unroll
            for (int r = 0; r < 8; ++r) rr[r] = sv1[r];
        } else if (t == 10) {
#pragma unroll
            for (int r = 0; r < 8; ++r) rr[r] = sv2[r];
        } else {
#pragma unroll
            for (int r = 0; r < 8; ++r) rr[r] = sv3[r];
        }
#pragma unroll
        for (int wk = TW - 1; wk >= 0; --wk) {
            const float g0v = rdlane(gA, wk);
            const float g1v = rdlane(gA, 16 + wk);
            const float g2v = rdlane(gA, 32 + wk);
            const float g3v = rdlane(gA, 48 + wk);
            const float g4v = rdlane(g4r, wk);
            const float cs = xo[dl][wk];
            A = sga_step(A, cs, g0v, g1v, g2v, g3v, g4v, is47, (t == NT - 1 && wk == TW - 1));
            const unsigned u = rr[wk >> 1];
            const float a0 = h2f((unsigned short)((wk & 1) ? (u >> 16) : (u & 0xffffu)));
            if (lane < Dd) xo[lane][wk] = fmaxf(A, a0);
        }
#pragma unroll
        for (int i = 0; i < 3; ++i) {
            float4 v;
            v.x = xo[srow[i]][scol[i] + 0];
            v.y = xo[srow[i]][scol[i] + 1];
            v.z = xo[srow[i]][scol[i] + 2];
            v.w = xo[srow[i]][scol[i] + 3];
            *reinterpret_cast<float4*>(orow + (size_t)srow[i] * HW + w0 + scol[i]) = v;
        }
        if (t > 0) {
#pragma unroll
            for (int i = 0; i < 3; ++i) {
                xo[srow[i]][scol[i] + 0] = pre[i].x;
                xo[srow[i]][scol[i] + 1] = pre[i].y;
                xo[srow[i]][scol[i] + 2] = pre[i].z;
                xo[srow[i]][scol[i] + 3] = pre[i].w;
            }
            gA = gAn;
            g4r = g4n;
        }
    }
}

// ============================================================================
// H-pair kernel sga_h8 (w4 recipe on the H axis): block = 8 waves, wave owns
// one w column (lane = d). Sequential fwd(gf) scan stashing a2 fp16 in 12
// static register banks (48 u32/lane), then rev(gr) scan combining stash +
// prefetched out, flushing via double-buffered osb tiles (h7's pipeline).
// LDS 62 KB (no cross-wave stash) -> 2 blocks/CU; 8-wave barrier groups.
// ============================================================================
constexpr int HWT = 8;            // w columns per block
constexpr int HKH = 8;            // h steps per tile
constexpr int HNT = Hh / HKH;     // 12 tiles

__global__ __launch_bounds__(512, 4) void sga_h8(const float* __restrict__ x,
                                                 const float* __restrict__ gf,
                                                 const float* __restrict__ gr,
                                                 float* __restrict__ out) {
    __shared__ float xs[2][HKH][Dd][HWT + 1];   // 27648 B
    __shared__ float gs[2][HKH][HWT][8];        // 8192 B  (k 0..4, pad 8)
    __shared__ float osb[2][HKH][Dd][HWT + 1];  // 27648 B
    // total 63488 B -> 2 blocks/CU

    // XCD pair-swizzle: the two blocks covering the 32B halves of each 64B
    // line are 8 apart in blockIdx -> same XCD. Grid = 768 = 8 * 96.
    const int xcd = blockIdx.x & 7;
    const int within = blockIdx.x >> 3;          // 0..95
    const int pairid = xcd * 48 + (within >> 1); // 0..383
    const int sub = within & 1;
    const int c = pairid / 12;
    const int w0 = ((pairid % 12) * 2 + sub) * HWT;

    const int tid = threadIdx.x;
    const int lane = tid & 63;
    const int col = tid >> 6;           // 0..7 -> w column
    const size_t HW = (size_t)Hh * Ww;

    const float* xb = x + (size_t)c * Dd * HW;
    const float* gfb = gf + (size_t)c * 5 * HW;
    const float* grb = gr + (size_t)c * 5 * HW;
    float* ob = out + (size_t)c * Dd * HW;

    const int dl = (lane < Dd) ? lane : (Dd - 1);
    const bool is47 = (lane == Dd - 1);

    // staging mapping: idx = tid + j*512 over [HKH=8][Dd=48][HWT=8] = 3072
    int w_[6], d_[6], hp_[6];
    size_t xoff_[6];
#pragma unroll
    for (int j = 0; j < 6; ++j) {
        const int idx = tid + j * 512;
        w_[j] = idx & 7;
        const int t = idx >> 3;
        d_[j] = t % Dd;
        hp_[j] = t / Dd;                 // 0..7
        xoff_[j] = (size_t)d_[j] * HW + (w0 + w_[j]);
    }
    // g staging (tid < 320): idx over [HKH=8][5k][HWT=8], w fastest
    const int gw_ = tid & 7;
    const int gk_ = (tid >> 3) % 5;
    const int ghp_ = (tid >> 3) / 5;     // 0..7
    const bool gst = tid < 320;

    float xr[6], grg = 0.f;
    unsigned tb[4];
    unsigned s0[4], s1[4], s2[4], s3[4], s4[4], s5[4];
    unsigned s6[4], s7[4], s8[4], s9[4], s10[4], s11[4];

    // ===== fwd prologue: stage tile 0 -> buf 0 =====
    {
#pragma unroll
        for (int j = 0; j < 6; ++j) xr[j] = xb[xoff_[j] + (size_t)hp_[j] * Ww];
        if (gst) grg = gfb[(size_t)gk_ * HW + (size_t)ghp_ * Ww + (w0 + gw_)];
#pragma unroll
        for (int j = 0; j < 6; ++j) xs[0][hp_[j]][d_[j]][w_[j]] = xr[j];
        if (gst) gs[0][ghp_][gw_][gk_] = grg;
    }
    __syncthreads();

    float A = NEGBIG;

    // ===== forward pass: a2 -> register stash (12 static banks) =====
#pragma unroll 2
    for (int t = 0; t < HNT; ++t) {
        const int pb = t & 1;
        if (t + 1 < HNT) {
            const int hb = (t + 1) * HKH;
#pragma unroll
            for (int j = 0; j < 6; ++j) xr[j] = xb[xoff_[j] + (size_t)(hb + hp_[j]) * Ww];
            if (gst) grg = gfb[(size_t)gk_ * HW + (size_t)(hb + ghp_) * Ww + (w0 + gw_)];
        }
#pragma unroll
        for (int hp = 0; hp < HKH; ++hp) {
            const float cs = xs[pb][hp][dl][col];
            const float* gb2 = &gs[pb][hp][col][0];
            const float4 g03 = *reinterpret_cast<const float4*>(gb2);
            const float g4 = gb2[4];
            A = sga_step(A, cs, g03.x, g03.y, g03.z, g03.w, g4, is47, (t == 0 && hp == 0));
            const unsigned hu = f2h(A);
            if ((hp & 1) == 0) tb[hp >> 1] = hu;
            else tb[hp >> 1] |= hu << 16;
        }
        // store stash bank t (wave-uniform branch)
        if (t == 0) {
#pragma unroll
            for (int i = 0; i < 4; ++i) s0[i] = tb[i];
        } else if (t == 1) {
#pragma unroll
            for (int i = 0; i < 4; ++i) s1[i] = tb[i];
        } else if (t == 2) {
#pragma unroll
            for (int i = 0; i < 4; ++i) s2[i] = tb[i];
        } else if (t == 3) {
#pragma unroll
            for (int i = 0; i < 4; ++i) s3[i] = tb[i];
        } else if (t == 4) {
#pragma unroll
            for (int i = 0; i < 4; ++i) s4[i] = tb[i];
        } else if (t == 5) {
#pragma unroll
            for (int i = 0; i < 4; ++i) s5[i] = tb[i];
        } else if (t == 6) {
#pragma unroll
            for (int i = 0; i < 4; ++i) s6[i] = tb[i];
        } else if (t == 7) {
#pragma unroll
            for (int i = 0; i < 4; ++i) s7[i] = tb[i];
        } else if (t == 8) {
#pragma unroll
            for (int i = 0; i < 4; ++i) s8[i] = tb[i];
        } else if (t == 9) {
#pragma unroll
            for (int i = 0; i < 4; ++i) s9[i] = tb[i];
        } else if (t == 10) {
#pragma unroll
            for (int i = 0; i < 4; ++i) s10[i] = tb[i];
        } else {
#pragma unroll
            for (int i = 0; i < 4; ++i) s11[i] = tb[i];
        }
        if (t + 1 < HNT) {
#pragma unroll
            for (int j = 0; j < 6; ++j) xs[pb ^ 1][hp_[j]][d_[j]][w_[j]] = xr[j];
            if (gst) gs[pb ^ 1][ghp_][gw_][gk_] = grg;
        }
        __syncthreads();
    }

    // ===== rev prologue: x tile 11 already in xs[1]; stage g(rev) tile 11 =====
    {
        if (gst) {
            grg = grb[(size_t)gk_ * HW + (size_t)((HNT - 1) * HKH + ghp_) * Ww + (w0 + gw_)];
            gs[1][ghp_][gw_][gk_] = grg;
        }
    }
    __syncthreads();

    // ===== reverse pass: combine with stash + out, flush pipelined =====
    A = NEGBIG;
    float orr[2][6];
#pragma unroll 2
    for (int r = 0; r < HNT; ++r) {
        const int t = HNT - 1 - r;
        const int pb = (r + 1) & 1;      // tile t resides in xs[pb]; r=0 -> 1

        // (1) stage loads for tile t-1
        if (r + 1 < HNT) {
            const int hb = (t - 1) * HKH;
#pragma unroll
            for (int j = 0; j < 6; ++j) xr[j] = xb[xoff_[j] + (size_t)(hb + hp_[j]) * Ww];
            if (gst) grg = grb[(size_t)gk_ * HW + (size_t)(hb + ghp_) * Ww + (w0 + gw_)];
        }
        // (2) out-reads for THIS tile t (consumed at next iteration's flush)
        {
            const int hb = t * HKH;
#pragma unroll
            for (int j = 0; j < 6; ++j)
                orr[pb][j] = ob[xoff_[j] + (size_t)(hb + hp_[j]) * Ww];
        }
        // (3) fetch stash bank t, compute 8 steps (hp = 7..0) -> osb[pb]
        unsigned rb[4];
        if (t == 0) {
#pragma unroll
            for (int i = 0; i < 4; ++i) rb[i] = s0[i];
        } else if (t == 1) {
#pragma unroll
            for (int i = 0; i < 4; ++i) rb[i] = s1[i];
        } else if (t == 2) {
#pragma unroll
            for (int i = 0; i < 4; ++i) rb[i] = s2[i];
        } else if (t == 3) {
#pragma unroll
            for (int i = 0; i < 4; ++i) rb[i] = s3[i];
        } else if (t == 4) {
#pragma unroll
            for (int i = 0; i < 4; ++i) rb[i] = s4[i];
        } else if (t == 5) {
#pragma unroll
            for (int i = 0; i < 4; ++i) rb[i] = s5[i];
        } else if (t == 6) {
#pragma unroll
            for (int i = 0; i < 4; ++i) rb[i] = s6[i];
        } else if (t == 7) {
#pragma unroll
            for (int i = 0; i < 4; ++i) rb[i] = s7[i];
        } else if (t == 8) {
#pragma unroll
            for (int i = 0; i < 4; ++i) rb[i] = s8[i];
        } else if (t == 9) {
#pragma unroll
            for (int i = 0; i < 4; ++i) rb[i] = s9[i];
        } else if (t == 10) {
#pragma unroll
            for (int i = 0; i < 4; ++i) rb[i] = s10[i];
        } else {
#pragma unroll
            for (int i = 0; i < 4; ++i) rb[i] = s11[i];
        }
#pragma unroll
        for (int hp = HKH - 1; hp >= 0; --hp) {
            const float cs = xs[pb][hp][dl][col];
            const float* gb2 = &gs[pb][hp][col][0];
            const float4 g03 = *reinterpret_cast<const float4*>(gb2);
            const float g4 = gb2[4];
            A = sga_step(A, cs, g03.x, g03.y, g03.z, g03.w, g4, is47,
                         (r == 0 && hp == HKH - 1));
            const unsigned u = rb[hp >> 1];
            const float a2 = h2f((unsigned short)((hp & 1) ? (u >> 16) : (u & 0xffffu)));
            if (lane < Dd) osb[pb][hp][lane][col] = fmaxf(A, a2);
        }
        // (4) flush previous tile (t+1) osb, combined with its out-reads
        if (r > 0) {
            const int hb = (t + 1) * HKH;
#pragma unroll
            for (int j = 0; j < 6; ++j) {
                const float v = fmaxf(osb[pb ^ 1][hp_[j]][d_[j]][w_[j]], orr[pb ^ 1][j]);
                ob[xoff_[j] + (size_t)(hb + hp_[j]) * Ww] = v;
            }
        }
        // (5) commit staged tile t-1 -> xs[pb^1]
        if (r + 1 < HNT) {
#pragma unroll
            for (int j = 0; j < 6; ++j) xs[pb ^ 1][hp_[j]][d_[j]][w_[j]] = xr[j];
            if (gst) gs[pb ^ 1][ghp_][gw_][gk_] = grg;
        }
        __syncthreads();
    }

    // epilogue: flush tile 0 (last computed, pb = (HNT)&1 = 0)
    {
#pragma unroll
        for (int j = 0; j < 6; ++j) {
            const float v = fmaxf(osb[0][hp_[j]][d_[j]][w_[j]], orr[0][j]);
            ob[xoff_[j] + (size_t)hp_[j] * Ww] = v;
        }
    }
}

extern "C" void kernel_launch(void* const* d_in, const int* in_sizes, int n_in,
                              void* d_out, int out_size, void* d_ws, size_t ws_size,
                              hipStream_t stream) {
    const float* x  = (const float*)d_in[0];
    const float* g0 = (const float*)d_in[1];
    const float* g1 = (const float*)d_in[2];
    const float* g2 = (const float*)d_in[3];
    const float* g3 = (const float*)d_in[4];
    float* out = (float*)d_out;

    // W pair: out = max(a0, a1)        (fwd stashes a0 on-chip, rev combines)
    sga_w4<<<Cc * Hh, 64, 0, stream>>>(x, g0, g1, out);
    // H pair: out = max(out, a2, a3)   (sequential fwd+rev, register stash)
    sga_h8<<<Cc * (Ww / HWT), 512, 0, stream>>>(x, g2, g3, out);
}

// Round 12
// 404.195 us; speedup vs baseline: 1.0793x; 1.0793x over previous
//
#include <hip/hip_runtime.h>

// Problem constants (B=1)
constexpr int Cc = 32;
constexpr int Dd = 48;
constexpr int Hh = 96;
constexpr int Ww = 192;
constexpr int TW = 16;           // W-kernel tile width
constexpr int NT = Ww / TW;      // 12 tiles
constexpr float NEGBIG = -3.402823466e+38f;

// ---- DPP helpers ------------------------------------------------------------
// NOTE: must use __builtin_amdgcn_update_dpp (not inline asm) — the compiler's
// hazard recognizer inserts the required VALU->DPP wait states only for
// compiler-known DPP ops. Inline-asm DPP caused silent corruption (round 3).
template <int CTRL, int RM>
__device__ __forceinline__ float dppmov(float v) {
    int i = __builtin_bit_cast(int, v);
    int r = __builtin_amdgcn_update_dpp(i, i, CTRL, RM, 0xF, false);
    return __builtin_bit_cast(float, r);
}

__device__ __forceinline__ float rdlane(float v, int idx) {
    int r = __builtin_amdgcn_readlane(__builtin_bit_cast(int, v), idx);
    return __builtin_bit_cast(float, r);
}

__device__ __forceinline__ unsigned f2h(float v) {
    return (unsigned)__builtin_bit_cast(unsigned short, (_Float16)v);
}
__device__ __forceinline__ float h2f(unsigned short u) {
    return (float)__builtin_bit_cast(_Float16, u);
}

// Max over lanes 0..47, broadcast. Row-confined: junk in lanes 48..63 never
// enters the reduction.
__device__ __forceinline__ float wave_max48(float v) {
    v = fmaxf(v, dppmov<0x111, 0xF>(v));   // row_shr:1
    v = fmaxf(v, dppmov<0x112, 0xF>(v));   // row_shr:2
    v = fmaxf(v, dppmov<0x114, 0xF>(v));   // row_shr:4
    v = fmaxf(v, dppmov<0x118, 0xF>(v));   // row_shr:8
    v = fmaxf(v, dppmov<0x142, 0x2>(v));   // row_bcast:15 -> row1: lane31=max(0..31)
    v = fmaxf(v, dppmov<0x143, 0x4>(v));   // row_bcast:31 -> row2: lane47=max(0..47)
    return rdlane(v, 47);
}

// One SGA step (lane = d). Lanes >= 48 compute garbage that never propagates
// back into lanes 0..47.
__device__ __forceinline__ float sga_step(float A, float cs, float g0v, float g1v, float g2v,
                                          float g3v, float g4v, bool is47, bool first) {
    float dm1 = dppmov<0x138, 0xF>(A);             // wave_shr:1, lane0 keeps own
    float dp1 = dppmov<0x130, 0xF>(A);             // wave_shl:1
    dp1 = is47 ? A : dp1;                          // d+1 clamp at d=47
    float mx = wave_max48(A);
    float r = g0v * cs + g1v * A + g2v * dm1 + g3v * dp1 + g4v * mx;
    return first ? cs : r;
}

// ============================================================================
// W-pair kernel sga_w5: w4's recipe with TWO rows per wave (2 independent
// chains interleaved -> 2x ILP fills the ~50% VALU issue gaps w4 showed).
// fwd scan (ga) stashes a0 fp16 on-chip (LDS tiles 0-7, reg banks 8-11, per
// row), rev scan (gb) combines and writes out = max(a0,a1) once per row.
// 1 wave/block, no barriers, 31 KB LDS -> 5 blocks/CU.
// ============================================================================
__global__ __launch_bounds__(64, 2) void sga_w5(const float* __restrict__ x,
                                                const float* __restrict__ ga,
                                                const float* __restrict__ gb,
                                                float* __restrict__ out) {
    __shared__ unsigned sstash0[64][Dd];  // row0, tiles 0..7: [t*8+r][lane]
    __shared__ unsigned sstash1[64][Dd];  // row1
    __shared__ float xoA[Dd][TW + 1];     // row0 x tile / flush tile
    __shared__ float xoB[Dd][TW + 1];     // row1

    const int bid = blockIdx.x;
    const int c = bid / (Hh / 2);
    const int h0 = (bid - c * (Hh / 2)) * 2;
    const int lane = threadIdx.x;
    const size_t HW = (size_t)Hh * Ww;

    const float* xrow0 = x + (size_t)c * Dd * HW + (size_t)h0 * Ww;
    const float* xrow1 = xrow0 + Ww;
    const float* garow0 = ga + (size_t)c * 5 * HW + (size_t)h0 * Ww;
    const float* garow1 = garow0 + Ww;
    const float* gbrow0 = gb + (size_t)c * 5 * HW + (size_t)h0 * Ww;
    const float* gbrow1 = gbrow0 + Ww;
    float* orow0 = out + (size_t)c * Dd * HW + (size_t)h0 * Ww;
    float* orow1 = orow0 + Ww;

    const int dl = (lane < Dd) ? lane : (Dd - 1);
    const bool is47 = (lane == Dd - 1);

    int srow[3], scol[3];
#pragma unroll
    for (int i = 0; i < 3; ++i) {
        const int e4 = lane + i * 64;
        srow[i] = e4 >> 2;
        scol[i] = (e4 & 3) * 4;
    }
    const int gk = lane >> 4;
    const int gwi = lane & 15;

    float4 preA[3], preB[3];
    float gA0, g40, gA1, g41;          // current g (rows 0,1)
    float gA0n = 0.f, g40n = 0.f, gA1n = 0.f, g41n = 0.f;
    unsigned trA[8], trB[8];
    unsigned a_sv0[8], a_sv1[8], a_sv2[8], a_sv3[8];
    unsigned b_sv0[8], b_sv1[8], b_sv2[8], b_sv3[8];

    // ===== prologue: x tile 0 (both rows) -> LDS, g(a) -> regs =====
    {
#pragma unroll
        for (int i = 0; i < 3; ++i) {
            preA[i] = *reinterpret_cast<const float4*>(xrow0 + (size_t)srow[i] * HW + scol[i]);
            preB[i] = *reinterpret_cast<const float4*>(xrow1 + (size_t)srow[i] * HW + scol[i]);
        }
        gA0 = garow0[(size_t)gk * HW + gwi];
        g40 = garow0[(size_t)4 * HW + gwi];
        gA1 = garow1[(size_t)gk * HW + gwi];
        g41 = garow1[(size_t)4 * HW + gwi];
#pragma unroll
        for (int i = 0; i < 3; ++i) {
            xoA[srow[i]][scol[i] + 0] = preA[i].x;
            xoA[srow[i]][scol[i] + 1] = preA[i].y;
            xoA[srow[i]][scol[i] + 2] = preA[i].z;
            xoA[srow[i]][scol[i] + 3] = preA[i].w;
            xoB[srow[i]][scol[i] + 0] = preB[i].x;
            xoB[srow[i]][scol[i] + 1] = preB[i].y;
            xoB[srow[i]][scol[i] + 2] = preB[i].z;
            xoB[srow[i]][scol[i] + 3] = preB[i].w;
        }
    }

    float A0 = NEGBIG, A1 = NEGBIG;

    // ===== forward: a0 -> on-chip fp16 stash (both rows) =====
    for (int t = 0; t < NT; ++t) {
        if (t + 1 < NT) {
            const int wn = (t + 1) * TW;
#pragma unroll
            for (int i = 0; i < 3; ++i) {
                preA[i] = *reinterpret_cast<const float4*>(xrow0 + (size_t)srow[i] * HW + wn + scol[i]);
                preB[i] = *reinterpret_cast<const float4*>(xrow1 + (size_t)srow[i] * HW + wn + scol[i]);
            }
            gA0n = garow0[(size_t)gk * HW + wn + gwi];
            g40n = garow0[(size_t)4 * HW + wn + gwi];
            gA1n = garow1[(size_t)gk * HW + wn + gwi];
            g41n = garow1[(size_t)4 * HW + wn + gwi];
        }
#pragma unroll 8
        for (int wk = 0; wk < TW; ++wk) {
            const bool first = (t == 0 && wk == 0);
            const float csA = xoA[dl][wk];
            const float csB = xoB[dl][wk];
            A0 = sga_step(A0, csA, rdlane(gA0, wk), rdlane(gA0, 16 + wk),
                          rdlane(gA0, 32 + wk), rdlane(gA0, 48 + wk), rdlane(g40, wk),
                          is47, first);
            A1 = sga_step(A1, csB, rdlane(gA1, wk), rdlane(gA1, 16 + wk),
                          rdlane(gA1, 32 + wk), rdlane(gA1, 48 + wk), rdlane(g41, wk),
                          is47, first);
            const unsigned huA = f2h(A0);
            const unsigned huB = f2h(A1);
            if ((wk & 1) == 0) {
                trA[wk >> 1] = huA;
                trB[wk >> 1] = huB;
            } else {
                trA[wk >> 1] |= huA << 16;
                trB[wk >> 1] |= huB << 16;
            }
        }
        if (t < 8) {
            if (lane < Dd) {
#pragma unroll
                for (int r = 0; r < 8; ++r) {
                    sstash0[t * 8 + r][lane] = trA[r];
                    sstash1[t * 8 + r][lane] = trB[r];
                }
            }
        } else if (t == 8) {
#pragma unroll
            for (int r = 0; r < 8; ++r) { a_sv0[r] = trA[r]; b_sv0[r] = trB[r]; }
        } else if (t == 9) {
#pragma unroll
            for (int r = 0; r < 8; ++r) { a_sv1[r] = trA[r]; b_sv1[r] = trB[r]; }
        } else if (t == 10) {
#pragma unroll
            for (int r = 0; r < 8; ++r) { a_sv2[r] = trA[r]; b_sv2[r] = trB[r]; }
        } else {
#pragma unroll
            for (int r = 0; r < 8; ++r) { a_sv3[r] = trA[r]; b_sv3[r] = trB[r]; }
        }
        if (t + 1 < NT) {
#pragma unroll
            for (int i = 0; i < 3; ++i) {
                xoA[srow[i]][scol[i] + 0] = preA[i].x;
                xoA[srow[i]][scol[i] + 1] = preA[i].y;
                xoA[srow[i]][scol[i] + 2] = preA[i].z;
                xoA[srow[i]][scol[i] + 3] = preA[i].w;
                xoB[srow[i]][scol[i] + 0] = preB[i].x;
                xoB[srow[i]][scol[i] + 1] = preB[i].y;
                xoB[srow[i]][scol[i] + 2] = preB[i].z;
                xoB[srow[i]][scol[i] + 3] = preB[i].w;
            }
            gA0 = gA0n; g40 = g40n; gA1 = gA1n; g41 = g41n;
        }
    }

    // ===== reverse + combine + single write (both rows) =====
    A0 = NEGBIG;
    A1 = NEGBIG;
    {
        const int w0 = (NT - 1) * TW;
        gA0 = gbrow0[(size_t)gk * HW + w0 + gwi];
        g40 = gbrow0[(size_t)4 * HW + w0 + gwi];
        gA1 = gbrow1[(size_t)gk * HW + w0 + gwi];
        g41 = gbrow1[(size_t)4 * HW + w0 + gwi];
    }
    for (int t = NT - 1; t >= 0; --t) {
        const int w0 = t * TW;
        if (t > 0) {
            const int wn = w0 - TW;
#pragma unroll
            for (int i = 0; i < 3; ++i) {
                preA[i] = *reinterpret_cast<const float4*>(xrow0 + (size_t)srow[i] * HW + wn + scol[i]);
                preB[i] = *reinterpret_cast<const float4*>(xrow1 + (size_t)srow[i] * HW + wn + scol[i]);
            }
            gA0n = gbrow0[(size_t)gk * HW + wn + gwi];
            g40n = gbrow0[(size_t)4 * HW + wn + gwi];
            gA1n = gbrow1[(size_t)gk * HW + wn + gwi];
            g41n = gbrow1[(size_t)4 * HW + wn + gwi];
        }
        unsigned rrA[8], rrB[8];
        if (t < 8) {
#pragma unroll
            for (int r = 0; r < 8; ++r) {
                rrA[r] = sstash0[t * 8 + r][dl];
                rrB[r] = sstash1[t * 8 + r][dl];
            }
        } else if (t == 8) {
#pragma unroll
            for (int r = 0; r < 8; ++r) { rrA[r] = a_sv0[r]; rrB[r] = b_sv0[r]; }
        } else if (t == 9) {
#pragma unroll
            for (int r = 0; r < 8; ++r) { rrA[r] = a_sv1[r]; rrB[r] = b_sv1[r]; }
        } else if (t == 10) {
#pragma unroll
            for (int r = 0; r < 8; ++r) { rrA[r] = a_sv2[r]; rrB[r] = b_sv2[r]; }
        } else {
#pragma unroll
            for (int r = 0; r < 8; ++r) { rrA[r] = a_sv3[r]; rrB[r] = b_sv3[r]; }
        }
#pragma unroll 8
        for (int wk = TW - 1; wk >= 0; --wk) {
            const bool first = (t == NT - 1 && wk == TW - 1);
            const float csA = xoA[dl][wk];
            const float csB = xoB[dl][wk];
            A0 = sga_step(A0, csA, rdlane(gA0, wk), rdlane(gA0, 16 + wk),
                          rdlane(gA0, 32 + wk), rdlane(gA0, 48 + wk), rdlane(g40, wk),
                          is47, first);
            A1 = sga_step(A1, csB, rdlane(gA1, wk), rdlane(gA1, 16 + wk),
                          rdlane(gA1, 32 + wk), rdlane(gA1, 48 + wk), rdlane(g41, wk),
                          is47, first);
            const unsigned uA = rrA[wk >> 1];
            const unsigned uB = rrB[wk >> 1];
            const float a0A = h2f((unsigned short)((wk & 1) ? (uA >> 16) : (uA & 0xffffu)));
            const float a0B = h2f((unsigned short)((wk & 1) ? (uB >> 16) : (uB & 0xffffu)));
            if (lane < Dd) {
                xoA[lane][wk] = fmaxf(A0, a0A);
                xoB[lane][wk] = fmaxf(A1, a0B);
            }
        }
#pragma unroll
        for (int i = 0; i < 3; ++i) {
            float4 v0, v1;
            v0.x = xoA[srow[i]][scol[i] + 0];
            v0.y = xoA[srow[i]][scol[i] + 1];
            v0.z = xoA[srow[i]][scol[i] + 2];
            v0.w = xoA[srow[i]][scol[i] + 3];
            v1.x = xoB[srow[i]][scol[i] + 0];
            v1.y = xoB[srow[i]][scol[i] + 1];
            v1.z = xoB[srow[i]][scol[i] + 2];
            v1.w = xoB[srow[i]][scol[i] + 3];
            *reinterpret_cast<float4*>(orow0 + (size_t)srow[i] * HW + w0 + scol[i]) = v0;
            *reinterpret_cast<float4*>(orow1 + (size_t)srow[i] * HW + w0 + scol[i]) = v1;
        }
        if (t > 0) {
#pragma unroll
            for (int i = 0; i < 3; ++i) {
                xoA[srow[i]][scol[i] + 0] = preA[i].x;
                xoA[srow[i]][scol[i] + 1] = preA[i].y;
                xoA[srow[i]][scol[i] + 2] = preA[i].z;
                xoA[srow[i]][scol[i] + 3] = preA[i].w;
                xoB[srow[i]][scol[i] + 0] = preB[i].x;
                xoB[srow[i]][scol[i] + 1] = preB[i].y;
                xoB[srow[i]][scol[i] + 2] = preB[i].z;
                xoB[srow[i]][scol[i] + 3] = preB[i].w;
            }
            gA0 = gA0n; g40 = g40n; gA1 = gA1n; g41 = g41n;
        }
    }
}

// ============================================================================
// H-pair kernel sga_h7 (round-10 verbatim, measured 169 us, clean writes):
// Block = 8 columns x 2 direction-waves = 16 waves (1024 thr), 1 block/CU.
// KH=4 (24 barriers). First 48 windows stash fp16; last 48 combine with the
// opposite chain's stash, single fp32 RMW of out: out = max(out, a2, a3).
// ============================================================================
constexpr int HWT = 8;
constexpr int HKH = 4;
constexpr int HNP = Hh / HKH;     // 24 periods
constexpr int HHALF = HNP / 2;    // 12

__global__ __launch_bounds__(1024) void sga_h7(const float* __restrict__ x,
                                               const float* __restrict__ gf,
                                               const float* __restrict__ gr,
                                               float* __restrict__ out) {
    __shared__ _Float16 stash[HWT][2][Hh / 2][Dd];   // 73728 B
    __shared__ float xs[2][2][HKH][Dd][9];           // 27648 B  (pad 9: conflict-free)
    __shared__ float osb[2][2][HKH][Dd][9];          // 27648 B
    __shared__ float gs[2][2][HKH][HWT][8];          // 8192 B   (8-pad: aligned float4)

    // XCD pair-swizzle: blocks covering the two 32B halves of each 64B line
    // (adjacent wt pairs) are 8 apart in blockIdx -> same XCD. Grid = 768.
    const int xcd = blockIdx.x & 7;
    const int within = blockIdx.x >> 3;          // 0..95
    const int pairid = xcd * 48 + (within >> 1); // 0..383
    const int sub = within & 1;
    const int c = pairid / 12;
    const int w0 = ((pairid % 12) * 2 + sub) * HWT;

    const int tid = threadIdx.x;
    const int lane = tid & 63;
    const int wv = tid >> 6;            // 0..15
    const int col = wv >> 1;            // 0..7
    const int dir = wv & 1;             // 0=fwd(h asc), 1=rev(h desc)
    const size_t HW = (size_t)Hh * Ww;

    const float* xb = x + (size_t)c * Dd * HW;
    const float* gfb = gf + (size_t)c * 5 * HW;
    const float* grb = gr + (size_t)c * 5 * HW;
    float* ob = out + (size_t)c * Dd * HW;

    const int dl = (lane < Dd) ? lane : (Dd - 1);
    const bool is47 = (lane == Dd - 1);

    // x / out staging decomposition: idx = tid + j*1024 over [2][HKH][Dd][HWT]
    int w_[3], d_[3], hp_[3], cu_[3];
    size_t xoff_[3];
#pragma unroll
    for (int j = 0; j < 3; ++j) {
        const int idx = tid + j * 1024;
        w_[j] = idx & 7;
        const int t = idx >> 3;
        d_[j] = t % Dd;
        const int t2 = t / Dd;
        hp_[j] = t2 & 3;
        cu_[j] = t2 >> 2;
        xoff_[j] = (size_t)d_[j] * HW + (w0 + w_[j]);
    }
    // g staging (tid < 320): idx over [2][HKH][5][HWT], w fastest (coalesced)
    const int gw_ = tid & 7;
    const int gk_ = (tid >> 3) % 5;
    const int ghc = (tid >> 3) / 5;       // 0..7
    const int ghp_ = ghc & 3;
    const int gcu_ = ghc >> 2;
    const bool gst = tid < 320;

    auto hofs = [&](int cur, int P, int hp) -> int {
        const int p = P * HKH + hp;
        return cur ? (Hh - 1 - p) : p;
    };

    float xr_[3], grg = 0.f, orr[2][3];

    // prologue: stage period 0 into buf 0
    {
#pragma unroll
        for (int j = 0; j < 3; ++j) xr_[j] = xb[xoff_[j] + (size_t)hofs(cu_[j], 0, hp_[j]) * Ww];
        if (gst) {
            const float* gp = gcu_ ? grb : gfb;
            grg = gp[(size_t)gk_ * HW + (size_t)hofs(gcu_, 0, ghp_) * Ww + (w0 + gw_)];
        }
#pragma unroll
        for (int j = 0; j < 3; ++j) xs[0][cu_[j]][hp_[j]][d_[j]][w_[j]] = xr_[j];
        if (gst) gs[0][gcu_][ghp_][gw_][gk_] = grg;
    }
    __syncthreads();

    float A = NEGBIG;

#pragma unroll 2
    for (int p = 0; p < HNP; ++p) {
        const int pb = p & 1;

        // (1) issue staging loads for period p+1
        if (p + 1 < HNP) {
#pragma unroll
            for (int j = 0; j < 3; ++j)
                xr_[j] = xb[xoff_[j] + (size_t)hofs(cu_[j], p + 1, hp_[j]) * Ww];
            if (gst) {
                const float* gp = gcu_ ? grb : gfb;
                grg = gp[(size_t)gk_ * HW + (size_t)hofs(gcu_, p + 1, ghp_) * Ww + (w0 + gw_)];
            }
        }
        // (2) issue out-reads for THIS period's osb (flushed next period)
        if (p >= HHALF) {
#pragma unroll
            for (int j = 0; j < 3; ++j)
                orr[pb][j] = ob[xoff_[j] + (size_t)hofs(cu_[j], p, hp_[j]) * Ww];
        }

        // (3) compute HKH windows
#pragma unroll
        for (int hp = 0; hp < HKH; ++hp) {
            const int q = p * HKH + hp;
            const float cs = xs[pb][dir][hp][dl][col];
            const float* gbase = &gs[pb][dir][hp][col][0];
            const float4 g03 = *reinterpret_cast<const float4*>(gbase);
            const float g4 = gbase[4];
            A = sga_step(A, cs, g03.x, g03.y, g03.z, g03.w, g4, is47, q == 0);
            if (q < Hh / 2) {
                if (lane < Dd) stash[col][dir][q][lane] = (_Float16)A;
            } else {
                const float s = (float)stash[col][dir ^ 1][Hh - 1 - q][dl];
                const float o = fmaxf(A, s);
                if (lane < Dd) osb[pb][dir][hp][lane][col] = o;
            }
        }

        // (4) flush period p-1 osb, combined with out-reads issued at p-1
        if (p > HHALF) {
#pragma unroll
            for (int j = 0; j < 3; ++j) {
                const float v = fmaxf(osb[pb ^ 1][cu_[j]][hp_[j]][d_[j]][w_[j]], orr[pb ^ 1][j]);
                ob[xoff_[j] + (size_t)hofs(cu_[j], p - 1, hp_[j]) * Ww] = v;
            }
        }

        // (5) commit staged regs for p+1
        if (p + 1 < HNP) {
#pragma unroll
            for (int j = 0; j < 3; ++j) xs[pb ^ 1][cu_[j]][hp_[j]][d_[j]][w_[j]] = xr_[j];
            if (gst) gs[pb ^ 1][gcu_][ghp_][gw_][gk_] = grg;
        }
        __syncthreads();
    }

    // epilogue: flush last period (p = HNP-1, pb = 1)
    {
#pragma unroll
        for (int j = 0; j < 3; ++j) {
            const float v = fmaxf(osb[1][cu_[j]][hp_[j]][d_[j]][w_[j]], orr[1][j]);
            ob[xoff_[j] + (size_t)hofs(cu_[j], HNP - 1, hp_[j]) * Ww] = v;
        }
    }
}

extern "C" void kernel_launch(void* const* d_in, const int* in_sizes, int n_in,
                              void* d_out, int out_size, void* d_ws, size_t ws_size,
                              hipStream_t stream) {
    const float* x  = (const float*)d_in[0];
    const float* g0 = (const float*)d_in[1];
    const float* g1 = (const float*)d_in[2];
    const float* g2 = (const float*)d_in[3];
    const float* g3 = (const float*)d_in[4];
    float* out = (float*)d_out;

    // W pair: out = max(a0, a1)        (2 rows/wave, on-chip stash, ILP x2)
    sga_w5<<<Cc * (Hh / 2), 64, 0, stream>>>(x, g0, g1, out);
    // H pair: out = max(out, a2, a3)   (fused both-dir, single fp32 RMW)
    sga_h7<<<Cc * (Ww / HWT), 1024, 0, stream>>>(x, g2, g3, out);
}

// Round 13
// 268.990 us; speedup vs baseline: 1.6218x; 1.5026x over previous
//
#include <hip/hip_runtime.h>

// Problem constants (B=1)
constexpr int Cc = 32;
constexpr int Dd = 48;
constexpr int Hh = 96;
constexpr int Ww = 192;
constexpr int TW = 16;           // W-kernel tile width
constexpr int NT = Ww / TW;      // 12 tiles
constexpr float NEGBIG = -3.402823466e+38f;

// ---- DPP helpers ------------------------------------------------------------
// NOTE: must use __builtin_amdgcn_update_dpp (not inline asm) — the compiler's
// hazard recognizer inserts the required VALU->DPP wait states only for
// compiler-known DPP ops. Inline-asm DPP caused silent corruption (round 3).
template <int CTRL, int RM>
__device__ __forceinline__ float dppmov(float v) {
    int i = __builtin_bit_cast(int, v);
    int r = __builtin_amdgcn_update_dpp(i, i, CTRL, RM, 0xF, false);
    return __builtin_bit_cast(float, r);
}

__device__ __forceinline__ float rdlane(float v, int idx) {
    int r = __builtin_amdgcn_readlane(__builtin_bit_cast(int, v), idx);
    return __builtin_bit_cast(float, r);
}

__device__ __forceinline__ unsigned f2h(float v) {
    return (unsigned)__builtin_bit_cast(unsigned short, (_Float16)v);
}
__device__ __forceinline__ float h2f(unsigned short u) {
    return (float)__builtin_bit_cast(_Float16, u);
}

// Max over lanes 0..47, broadcast. Row-confined: junk in lanes 48..63 never
// enters the reduction.
__device__ __forceinline__ float wave_max48(float v) {
    v = fmaxf(v, dppmov<0x111, 0xF>(v));   // row_shr:1
    v = fmaxf(v, dppmov<0x112, 0xF>(v));   // row_shr:2
    v = fmaxf(v, dppmov<0x114, 0xF>(v));   // row_shr:4
    v = fmaxf(v, dppmov<0x118, 0xF>(v));   // row_shr:8
    v = fmaxf(v, dppmov<0x142, 0x2>(v));   // row_bcast:15 -> row1: lane31=max(0..31)
    v = fmaxf(v, dppmov<0x143, 0x4>(v));   // row_bcast:31 -> row2: lane47=max(0..47)
    return rdlane(v, 47);
}

// One SGA step (lane = d). Lanes >= 48 compute garbage that never propagates
// back into lanes 0..47.
__device__ __forceinline__ float sga_step(float A, float cs, float g0v, float g1v, float g2v,
                                          float g3v, float g4v, bool is47, bool first) {
    float dm1 = dppmov<0x138, 0xF>(A);             // wave_shr:1, lane0 keeps own
    float dp1 = dppmov<0x130, 0xF>(A);             // wave_shl:1
    dp1 = is47 ? A : dp1;                          // d+1 clamp at d=47
    float mx = wave_max48(A);
    float r = g0v * cs + g1v * A + g2v * dm1 + g3v * dp1 + g4v * mx;
    return first ? cs : r;
}

// ============================================================================
// W-pair kernel (proven best, rounds 6-10, ~100-103 us): fwd scan (ga)
// stashes a0 fp16 on-chip (LDS tiles 0-7, static reg banks 8-11), rev scan
// (gb) combines, writes out = max(a0,a1) once. 1 wave/block, no barriers,
// 15.6 KB LDS -> ~10 blocks/CU. Wave-count > in-wave ILP (round-12 lesson).
// ============================================================================
__global__ __launch_bounds__(64, 4) void sga_w4(const float* __restrict__ x,
                                                const float* __restrict__ ga,
                                                const float* __restrict__ gb,
                                                float* __restrict__ out) {
    __shared__ unsigned sstash[64][Dd];   // tiles 0..7, [t*8+r][lane]
    __shared__ float xo[Dd][TW + 1];      // x tile / flush tile

    const int bid = blockIdx.x;
    const int c = bid / Hh;
    const int h = bid - c * Hh;
    const int lane = threadIdx.x;
    const size_t HW = (size_t)Hh * Ww;

    const float* xrow = x + (size_t)c * Dd * HW + (size_t)h * Ww;
    const float* garow = ga + (size_t)c * 5 * HW + (size_t)h * Ww;
    const float* gbrow = gb + (size_t)c * 5 * HW + (size_t)h * Ww;
    float* orow = out + (size_t)c * Dd * HW + (size_t)h * Ww;

    const int dl = (lane < Dd) ? lane : (Dd - 1);
    const bool is47 = (lane == Dd - 1);

    int srow[3], scol[3];
#pragma unroll
    for (int i = 0; i < 3; ++i) {
        const int e4 = lane + i * 64;
        srow[i] = e4 >> 2;
        scol[i] = (e4 & 3) * 4;
    }
    const int gk = lane >> 4;
    const int gwi = lane & 15;

    float4 pre[3];
    float gA, g4r, gAn = 0.f, g4n = 0.f;
    unsigned tr[8];
    unsigned sv0[8], sv1[8], sv2[8], sv3[8];

    {
#pragma unroll
        for (int i = 0; i < 3; ++i)
            pre[i] = *reinterpret_cast<const float4*>(xrow + (size_t)srow[i] * HW + scol[i]);
        gA = garow[(size_t)gk * HW + gwi];
        g4r = garow[(size_t)4 * HW + gwi];
#pragma unroll
        for (int i = 0; i < 3; ++i) {
            xo[srow[i]][scol[i] + 0] = pre[i].x;
            xo[srow[i]][scol[i] + 1] = pre[i].y;
            xo[srow[i]][scol[i] + 2] = pre[i].z;
            xo[srow[i]][scol[i] + 3] = pre[i].w;
        }
    }

    float A = NEGBIG;

    // forward: a0 -> on-chip fp16 stash
    for (int t = 0; t < NT; ++t) {
        if (t + 1 < NT) {
            const int wn = (t + 1) * TW;
#pragma unroll
            for (int i = 0; i < 3; ++i)
                pre[i] = *reinterpret_cast<const float4*>(xrow + (size_t)srow[i] * HW + wn + scol[i]);
            gAn = garow[(size_t)gk * HW + wn + gwi];
            g4n = garow[(size_t)4 * HW + wn + gwi];
        }
#pragma unroll
        for (int wk = 0; wk < TW; ++wk) {
            const float g0v = rdlane(gA, wk);
            const float g1v = rdlane(gA, 16 + wk);
            const float g2v = rdlane(gA, 32 + wk);
            const float g3v = rdlane(gA, 48 + wk);
            const float g4v = rdlane(g4r, wk);
            const float cs = xo[dl][wk];
            A = sga_step(A, cs, g0v, g1v, g2v, g3v, g4v, is47, (t == 0 && wk == 0));
            const unsigned hu = f2h(A);
            if ((wk & 1) == 0) tr[wk >> 1] = hu;
            else tr[wk >> 1] |= hu << 16;
        }
        if (t < 8) {
            if (lane < Dd) {
#pragma unroll
                for (int r = 0; r < 8; ++r) sstash[t * 8 + r][lane] = tr[r];
            }
        } else if (t == 8) {
#pragma unroll
            for (int r = 0; r < 8; ++r) sv0[r] = tr[r];
        } else if (t == 9) {
#pragma unroll
            for (int r = 0; r < 8; ++r) sv1[r] = tr[r];
        } else if (t == 10) {
#pragma unroll
            for (int r = 0; r < 8; ++r) sv2[r] = tr[r];
        } else {
#pragma unroll
            for (int r = 0; r < 8; ++r) sv3[r] = tr[r];
        }
        if (t + 1 < NT) {
#pragma unroll
            for (int i = 0; i < 3; ++i) {
                xo[srow[i]][scol[i] + 0] = pre[i].x;
                xo[srow[i]][scol[i] + 1] = pre[i].y;
                xo[srow[i]][scol[i] + 2] = pre[i].z;
                xo[srow[i]][scol[i] + 3] = pre[i].w;
            }
            gA = gAn;
            g4r = g4n;
        }
    }

    // reverse + combine + single write
    A = NEGBIG;
    {
        const int w0 = (NT - 1) * TW;
        gA = gbrow[(size_t)gk * HW + w0 + gwi];
        g4r = gbrow[(size_t)4 * HW + w0 + gwi];
    }
    for (int t = NT - 1; t >= 0; --t) {
        const int w0 = t * TW;
        if (t > 0) {
            const int wn = w0 - TW;
#pragma unroll
            for (int i = 0; i < 3; ++i)
                pre[i] = *reinterpret_cast<const float4*>(xrow + (size_t)srow[i] * HW + wn + scol[i]);
            gAn = gbrow[(size_t)gk * HW + wn + gwi];
            g4n = gbrow[(size_t)4 * HW + wn + gwi];
        }
        unsigned rr[8];
        if (t < 8) {
#pragma unroll
            for (int r = 0; r < 8; ++r) rr[r] = sstash[t * 8 + r][dl];
        } else if (t == 8) {
#pragma unroll
            for (int r = 0; r < 8; ++r) rr[r] = sv0[r];
        } else if (t == 9) {
#pragma unroll
            for (int r = 0; r < 8; ++r) rr[r] = sv1[r];
        } else if (t == 10) {
#pragma unroll
            for (int r = 0; r < 8; ++r) rr[r] = sv2[r];
        } else {
#pragma unroll
            for (int r = 0; r < 8; ++r) rr[r] = sv3[r];
        }
#pragma unroll
        for (int wk = TW - 1; wk >= 0; --wk) {
            const float g0v = rdlane(gA, wk);
            const float g1v = rdlane(gA, 16 + wk);
            const float g2v = rdlane(gA, 32 + wk);
            const float g3v = rdlane(gA, 48 + wk);
            const float g4v = rdlane(g4r, wk);
            const float cs = xo[dl][wk];
            A = sga_step(A, cs, g0v, g1v, g2v, g3v, g4v, is47, (t == NT - 1 && wk == TW - 1));
            const unsigned u = rr[wk >> 1];
            const float a0 = h2f((unsigned short)((wk & 1) ? (u >> 16) : (u & 0xffffu)));
            if (lane < Dd) xo[lane][wk] = fmaxf(A, a0);
        }
#pragma unroll
        for (int i = 0; i < 3; ++i) {
            float4 v;
            v.x = xo[srow[i]][scol[i] + 0];
            v.y = xo[srow[i]][scol[i] + 1];
            v.z = xo[srow[i]][scol[i] + 2];
            v.w = xo[srow[i]][scol[i] + 3];
            *reinterpret_cast<float4*>(orow + (size_t)srow[i] * HW + w0 + scol[i]) = v;
        }
        if (t > 0) {
#pragma unroll
            for (int i = 0; i < 3; ++i) {
                xo[srow[i]][scol[i] + 0] = pre[i].x;
                xo[srow[i]][scol[i] + 1] = pre[i].y;
                xo[srow[i]][scol[i] + 2] = pre[i].z;
                xo[srow[i]][scol[i] + 3] = pre[i].w;
            }
            gA = gAn;
            g4r = g4n;
        }
    }
}

// ============================================================================
// H-pair kernel sga_h7 (proven best, round-10, ~169 us, clean 110.6 MB
// writes): Block = 8 columns x 2 direction-waves = 16 waves (1024 thr),
// 1 block/CU. KH=4 (24 barriers). First 48 windows stash fp16; last 48
// combine with the opposite chain's stash, single fp32 RMW of out with
// 32B-sector-aligned stores: out = max(out, a2, a3).
// ============================================================================
constexpr int HWT = 8;
constexpr int HKH = 4;
constexpr int HNP = Hh / HKH;     // 24 periods
constexpr int HHALF = HNP / 2;    // 12

__global__ __launch_bounds__(1024) void sga_h7(const float* __restrict__ x,
                                               const float* __restrict__ gf,
                                               const float* __restrict__ gr,
                                               float* __restrict__ out) {
    __shared__ _Float16 stash[HWT][2][Hh / 2][Dd];   // 73728 B
    __shared__ float xs[2][2][HKH][Dd][9];           // 27648 B  (pad 9: conflict-free)
    __shared__ float osb[2][2][HKH][Dd][9];          // 27648 B
    __shared__ float gs[2][2][HKH][HWT][8];          // 8192 B   (8-pad: aligned float4)

    // XCD pair-swizzle: blocks covering the two 32B halves of each 64B line
    // (adjacent wt pairs) are 8 apart in blockIdx -> same XCD. Grid = 768.
    const int xcd = blockIdx.x & 7;
    const int within = blockIdx.x >> 3;          // 0..95
    const int pairid = xcd * 48 + (within >> 1); // 0..383
    const int sub = within & 1;
    const int c = pairid / 12;
    const int w0 = ((pairid % 12) * 2 + sub) * HWT;

    const int tid = threadIdx.x;
    const int lane = tid & 63;
    const int wv = tid >> 6;            // 0..15
    const int col = wv >> 1;            // 0..7
    const int dir = wv & 1;             // 0=fwd(h asc), 1=rev(h desc)
    const size_t HW = (size_t)Hh * Ww;

    const float* xb = x + (size_t)c * Dd * HW;
    const float* gfb = gf + (size_t)c * 5 * HW;
    const float* grb = gr + (size_t)c * 5 * HW;
    float* ob = out + (size_t)c * Dd * HW;

    const int dl = (lane < Dd) ? lane : (Dd - 1);
    const bool is47 = (lane == Dd - 1);

    // x / out staging decomposition: idx = tid + j*1024 over [2][HKH][Dd][HWT]
    int w_[3], d_[3], hp_[3], cu_[3];
    size_t xoff_[3];
#pragma unroll
    for (int j = 0; j < 3; ++j) {
        const int idx = tid + j * 1024;
        w_[j] = idx & 7;
        const int t = idx >> 3;
        d_[j] = t % Dd;
        const int t2 = t / Dd;
        hp_[j] = t2 & 3;
        cu_[j] = t2 >> 2;
        xoff_[j] = (size_t)d_[j] * HW + (w0 + w_[j]);
    }
    // g staging (tid < 320): idx over [2][HKH][5][HWT], w fastest (coalesced)
    const int gw_ = tid & 7;
    const int gk_ = (tid >> 3) % 5;
    const int ghc = (tid >> 3) / 5;       // 0..7
    const int ghp_ = ghc & 3;
    const int gcu_ = ghc >> 2;
    const bool gst = tid < 320;

    auto hofs = [&](int cur, int P, int hp) -> int {
        const int p = P * HKH + hp;
        return cur ? (Hh - 1 - p) : p;
    };

    float xr_[3], grg = 0.f, orr[2][3];

    // prologue: stage period 0 into buf 0
    {
#pragma unroll
        for (int j = 0; j < 3; ++j) xr_[j] = xb[xoff_[j] + (size_t)hofs(cu_[j], 0, hp_[j]) * Ww];
        if (gst) {
            const float* gp = gcu_ ? grb : gfb;
            grg = gp[(size_t)gk_ * HW + (size_t)hofs(gcu_, 0, ghp_) * Ww + (w0 + gw_)];
        }
#pragma unroll
        for (int j = 0; j < 3; ++j) xs[0][cu_[j]][hp_[j]][d_[j]][w_[j]] = xr_[j];
        if (gst) gs[0][gcu_][ghp_][gw_][gk_] = grg;
    }
    __syncthreads();

    float A = NEGBIG;

#pragma unroll 2
    for (int p = 0; p < HNP; ++p) {
        const int pb = p & 1;

        // (1) issue staging loads for period p+1
        if (p + 1 < HNP) {
#pragma unroll
            for (int j = 0; j < 3; ++j)
                xr_[j] = xb[xoff_[j] + (size_t)hofs(cu_[j], p + 1, hp_[j]) * Ww];
            if (gst) {
                const float* gp = gcu_ ? grb : gfb;
                grg = gp[(size_t)gk_ * HW + (size_t)hofs(gcu_, p + 1, ghp_) * Ww + (w0 + gw_)];
            }
        }
        // (2) issue out-reads for THIS period's osb (flushed next period)
        if (p >= HHALF) {
#pragma unroll
            for (int j = 0; j < 3; ++j)
                orr[pb][j] = ob[xoff_[j] + (size_t)hofs(cu_[j], p, hp_[j]) * Ww];
        }

        // (3) compute HKH windows
#pragma unroll
        for (int hp = 0; hp < HKH; ++hp) {
            const int q = p * HKH + hp;
            const float cs = xs[pb][dir][hp][dl][col];
            const float* gbase = &gs[pb][dir][hp][col][0];
            const float4 g03 = *reinterpret_cast<const float4*>(gbase);
            const float g4 = gbase[4];
            A = sga_step(A, cs, g03.x, g03.y, g03.z, g03.w, g4, is47, q == 0);
            if (q < Hh / 2) {
                if (lane < Dd) stash[col][dir][q][lane] = (_Float16)A;
            } else {
                const float s = (float)stash[col][dir ^ 1][Hh - 1 - q][dl];
                const float o = fmaxf(A, s);
                if (lane < Dd) osb[pb][dir][hp][lane][col] = o;
            }
        }

        // (4) flush period p-1 osb, combined with out-reads issued at p-1
        if (p > HHALF) {
#pragma unroll
            for (int j = 0; j < 3; ++j) {
                const float v = fmaxf(osb[pb ^ 1][cu_[j]][hp_[j]][d_[j]][w_[j]], orr[pb ^ 1][j]);
                ob[xoff_[j] + (size_t)hofs(cu_[j], p - 1, hp_[j]) * Ww] = v;
            }
        }

        // (5) commit staged regs for p+1
        if (p + 1 < HNP) {
#pragma unroll
            for (int j = 0; j < 3; ++j) xs[pb ^ 1][cu_[j]][hp_[j]][d_[j]][w_[j]] = xr_[j];
            if (gst) gs[pb ^ 1][gcu_][ghp_][gw_][gk_] = grg;
        }
        __syncthreads();
    }

    // epilogue: flush last period (p = HNP-1, pb = 1)
    {
#pragma unroll
        for (int j = 0; j < 3; ++j) {
            const float v = fmaxf(osb[1][cu_[j]][hp_[j]][d_[j]][w_[j]], orr[1][j]);
            ob[xoff_[j] + (size_t)hofs(cu_[j], HNP - 1, hp_[j]) * Ww] = v;
        }
    }
}

extern "C" void kernel_launch(void* const* d_in, const int* in_sizes, int n_in,
                              void* d_out, int out_size, void* d_ws, size_t ws_size,
                              hipStream_t stream) {
    const float* x  = (const float*)d_in[0];
    const float* g0 = (const float*)d_in[1];
    const float* g1 = (const float*)d_in[2];
    const float* g2 = (const float*)d_in[3];
    const float* g3 = (const float*)d_in[4];
    float* out = (float*)d_out;

    // W pair: out = max(a0, a1)        (fwd stashes a0 on-chip, rev combines)
    sga_w4<<<Cc * Hh, 64, 0, stream>>>(x, g0, g1, out);
    // H pair: out = max(out, a2, a3)   (fused both-dir, single fp32 RMW)
    sga_h7<<<Cc * (Ww / HWT), 1024, 0, stream>>>(x, g2, g3, out);
}

// Round 14
// 250.435 us; speedup vs baseline: 1.7420x; 1.0741x over previous
//
#include <hip/hip_runtime.h>

// Problem constants (B=1)
constexpr int Cc = 32;
constexpr int Dd = 48;
constexpr int Hh = 96;
constexpr int Ww = 192;
constexpr int TW = 16;           // W-kernel tile width
constexpr int NT = Ww / TW;      // 12 tiles
constexpr float NEGBIG = -3.402823466e+38f;

// ---- DPP helpers ------------------------------------------------------------
// NOTE: must use __builtin_amdgcn_update_dpp (not inline asm) — the compiler's
// hazard recognizer inserts the required VALU->DPP wait states only for
// compiler-known DPP ops. Inline-asm DPP caused silent corruption (round 3).
template <int CTRL, int RM>
__device__ __forceinline__ float dppmov(float v) {
    int i = __builtin_bit_cast(int, v);
    int r = __builtin_amdgcn_update_dpp(i, i, CTRL, RM, 0xF, false);
    return __builtin_bit_cast(float, r);
}

__device__ __forceinline__ float rdlane(float v, int idx) {
    int r = __builtin_amdgcn_readlane(__builtin_bit_cast(int, v), idx);
    return __builtin_bit_cast(float, r);
}

__device__ __forceinline__ unsigned f2h(float v) {
    return (unsigned)__builtin_bit_cast(unsigned short, (_Float16)v);
}
__device__ __forceinline__ float h2f(unsigned short u) {
    return (float)__builtin_bit_cast(_Float16, u);
}

// Max over lanes 0..47, broadcast. Row-confined: junk in lanes 48..63 never
// enters the reduction.
__device__ __forceinline__ float wave_max48(float v) {
    v = fmaxf(v, dppmov<0x111, 0xF>(v));   // row_shr:1
    v = fmaxf(v, dppmov<0x112, 0xF>(v));   // row_shr:2
    v = fmaxf(v, dppmov<0x114, 0xF>(v));   // row_shr:4
    v = fmaxf(v, dppmov<0x118, 0xF>(v));   // row_shr:8
    v = fmaxf(v, dppmov<0x142, 0x2>(v));   // row_bcast:15 -> row1: lane31=max(0..31)
    v = fmaxf(v, dppmov<0x143, 0x4>(v));   // row_bcast:31 -> row2: lane47=max(0..47)
    return rdlane(v, 47);
}

// One SGA step (lane = d). Lanes >= 48 compute garbage that never propagates
// back into lanes 0..47.
__device__ __forceinline__ float sga_step(float A, float cs, float g0v, float g1v, float g2v,
                                          float g3v, float g4v, bool is47, bool first) {
    float dm1 = dppmov<0x138, 0xF>(A);             // wave_shr:1, lane0 keeps own
    float dp1 = dppmov<0x130, 0xF>(A);             // wave_shl:1
    dp1 = is47 ? A : dp1;                          // d+1 clamp at d=47
    float mx = wave_max48(A);
    float r = g0v * cs + g1v * A + g2v * dm1 + g3v * dp1 + g4v * mx;
    return first ? cs : r;
}

// 16 recurrence steps over one tile. DESC = scan direction within the tile.
// STASH = pack results fp16 into tr (first-visit-assign, second-visit-OR);
// else combine with opposite stash rr and write results to xo.
template <bool DESC, bool STASH>
__device__ __forceinline__ void w6_run16(float& A, unsigned* tr, const unsigned* rr,
                                         float (*xo)[TW + 1], float gA, float g4r,
                                         int lane, int dl, bool is47, bool firstTile) {
#pragma unroll
    for (int k = 0; k < TW; ++k) {
        const int wk = DESC ? (TW - 1 - k) : k;
        const float g0v = rdlane(gA, wk);
        const float g1v = rdlane(gA, 16 + wk);
        const float g2v = rdlane(gA, 32 + wk);
        const float g3v = rdlane(gA, 48 + wk);
        const float g4v = rdlane(g4r, wk);
        const float cs = xo[dl][wk];
        A = sga_step(A, cs, g0v, g1v, g2v, g3v, g4v, is47, firstTile && (k == 0));
        if (STASH) {
            const unsigned hu = f2h(A);
            if (!DESC) {
                if ((wk & 1) == 0) tr[wk >> 1] = hu;
                else tr[wk >> 1] |= hu << 16;
            } else {
                if (wk & 1) tr[wk >> 1] = hu << 16;
                else tr[wk >> 1] |= hu;
            }
        } else {
            const unsigned u = rr[wk >> 1];
            const float aop = h2f((unsigned short)((wk & 1) ? (u >> 16) : (u & 0xffffu)));
            if (lane < Dd) xo[lane][wk] = fmaxf(A, aop);
        }
    }
}

// ============================================================================
// W-pair kernel sga_w6: meet-in-the-middle. Block = 2 waves on one (c,h) row;
// wave0 = fwd scan (ga), wave1 = rev scan (gb) run SIMULTANEOUSLY (96-step
// serial chain per wave instead of w4's 384). First 6 tiles each wave stashes
// fp16-packed a-values to LDS; one barrier; last 6 tiles combine with the
// opposite wave's stash and write out = max(a0,a1) once (64B-line stores).
// LDS 24.9 KB -> 6 blocks/CU (12 waves/CU, more TLP than w4's 10).
// ============================================================================
__global__ __launch_bounds__(128, 4) void sga_w6(const float* __restrict__ x,
                                                 const float* __restrict__ ga,
                                                 const float* __restrict__ gb,
                                                 float* __restrict__ out) {
    __shared__ unsigned sstash[2][48][Dd];   // [dir][lt*8+r][lane] u32 = 18432 B
    __shared__ float xo[2][Dd][TW + 1];      // per-dir x tile / flush tile = 6528 B

    const int bid = blockIdx.x;
    const int c = bid / Hh;
    const int h = bid - c * Hh;
    const int tid = threadIdx.x;
    const int lane = tid & 63;
    const int dir = tid >> 6;            // 0 = fwd (w asc, ga), 1 = rev (w desc, gb)
    const size_t HW = (size_t)Hh * Ww;

    const float* xrow = x + (size_t)c * Dd * HW + (size_t)h * Ww;
    const float* grow = (dir ? gb : ga) + (size_t)c * 5 * HW + (size_t)h * Ww;
    float* orow = out + (size_t)c * Dd * HW + (size_t)h * Ww;

    const int dl = (lane < Dd) ? lane : (Dd - 1);
    const bool is47 = (lane == Dd - 1);

    int srow[3], scol[3];
#pragma unroll
    for (int i = 0; i < 3; ++i) {
        const int e4 = lane + i * 64;
        srow[i] = e4 >> 2;
        scol[i] = (e4 & 3) * 4;
    }
    const int gk = lane >> 4;
    const int gwi = lane & 15;

    float4 pre[3];
    float gA, g4r, gAn = 0.f, g4n = 0.f;
    unsigned tr[8];

    // prologue: first tile of own direction -> own xo half
    {
        const int t = dir ? (NT - 1) : 0;
        const int w0 = t * TW;
#pragma unroll
        for (int i = 0; i < 3; ++i)
            pre[i] = *reinterpret_cast<const float4*>(xrow + (size_t)srow[i] * HW + w0 + scol[i]);
        gA = grow[(size_t)gk * HW + w0 + gwi];
        g4r = grow[(size_t)4 * HW + w0 + gwi];
#pragma unroll
        for (int i = 0; i < 3; ++i) {
            xo[dir][srow[i]][scol[i] + 0] = pre[i].x;
            xo[dir][srow[i]][scol[i] + 1] = pre[i].y;
            xo[dir][srow[i]][scol[i] + 2] = pre[i].z;
            xo[dir][srow[i]][scol[i] + 3] = pre[i].w;
        }
    }

    float A = NEGBIG;

    for (int tt = 0; tt < NT; ++tt) {
        if (tt == NT / 2) __syncthreads();   // opposite stash complete

        const int t = dir ? (NT - 1 - tt) : tt;
        const int w0 = t * TW;

        // prefetch next tile of own direction (hidden under the 16-step chain)
        if (tt + 1 < NT) {
            const int wn = (dir ? (NT - 2 - tt) : (tt + 1)) * TW;
#pragma unroll
            for (int i = 0; i < 3; ++i)
                pre[i] = *reinterpret_cast<const float4*>(xrow + (size_t)srow[i] * HW + wn + scol[i]);
            gAn = grow[(size_t)gk * HW + wn + gwi];
            g4n = grow[(size_t)4 * HW + wn + gwi];
        }

        unsigned rr[8];
        if (tt >= NT / 2) {
            // opposite wave stashed tile t at local index NT-1-tt
#pragma unroll
            for (int r = 0; r < 8; ++r) rr[r] = sstash[dir ^ 1][(NT - 1 - tt) * 8 + r][dl];
        }

        if (tt < NT / 2) {
            if (dir == 0)
                w6_run16<false, true>(A, tr, rr, xo[0], gA, g4r, lane, dl, is47, tt == 0);
            else
                w6_run16<true, true>(A, tr, rr, xo[1], gA, g4r, lane, dl, is47, tt == 0);
            if (lane < Dd) {
#pragma unroll
                for (int r = 0; r < 8; ++r) sstash[dir][tt * 8 + r][lane] = tr[r];
            }
        } else {
            if (dir == 0)
                w6_run16<false, false>(A, tr, rr, xo[0], gA, g4r, lane, dl, is47, false);
            else
                w6_run16<true, false>(A, tr, rr, xo[1], gA, g4r, lane, dl, is47, false);
            // flush combined tile (coalesced float4, full 64B lines)
#pragma unroll
            for (int i = 0; i < 3; ++i) {
                float4 v;
                v.x = xo[dir][srow[i]][scol[i] + 0];
                v.y = xo[dir][srow[i]][scol[i] + 1];
                v.z = xo[dir][srow[i]][scol[i] + 2];
                v.w = xo[dir][srow[i]][scol[i] + 3];
                *reinterpret_cast<float4*>(orow + (size_t)srow[i] * HW + w0 + scol[i]) = v;
            }
        }

        if (tt + 1 < NT) {
#pragma unroll
            for (int i = 0; i < 3; ++i) {
                xo[dir][srow[i]][scol[i] + 0] = pre[i].x;
                xo[dir][srow[i]][scol[i] + 1] = pre[i].y;
                xo[dir][srow[i]][scol[i] + 2] = pre[i].z;
                xo[dir][srow[i]][scol[i] + 3] = pre[i].w;
            }
            gA = gAn;
            g4r = g4n;
        }
    }
}

// ============================================================================
// H-pair kernel sga_h7 (proven best, rounds 10/13, ~163-169 us, clean
// 110.6 MB writes): Block = 8 columns x 2 direction-waves = 16 waves
// (1024 thr), 1 block/CU. KH=4 (24 barriers). First 48 windows stash fp16;
// last 48 combine with the opposite chain's stash, single fp32 RMW of out
// with 32B-sector-aligned stores: out = max(out, a2, a3).
// ============================================================================
constexpr int HWT = 8;
constexpr int HKH = 4;
constexpr int HNP = Hh / HKH;     // 24 periods
constexpr int HHALF = HNP / 2;    // 12

__global__ __launch_bounds__(1024) void sga_h7(const float* __restrict__ x,
                                               const float* __restrict__ gf,
                                               const float* __restrict__ gr,
                                               float* __restrict__ out) {
    __shared__ _Float16 stash[HWT][2][Hh / 2][Dd];   // 73728 B
    __shared__ float xs[2][2][HKH][Dd][9];           // 27648 B  (pad 9: conflict-free)
    __shared__ float osb[2][2][HKH][Dd][9];          // 27648 B
    __shared__ float gs[2][2][HKH][HWT][8];          // 8192 B   (8-pad: aligned float4)

    // XCD pair-swizzle: blocks covering the two 32B halves of each 64B line
    // (adjacent wt pairs) are 8 apart in blockIdx -> same XCD. Grid = 768.
    const int xcd = blockIdx.x & 7;
    const int within = blockIdx.x >> 3;          // 0..95
    const int pairid = xcd * 48 + (within >> 1); // 0..383
    const int sub = within & 1;
    const int c = pairid / 12;
    const int w0 = ((pairid % 12) * 2 + sub) * HWT;

    const int tid = threadIdx.x;
    const int lane = tid & 63;
    const int wv = tid >> 6;            // 0..15
    const int col = wv >> 1;            // 0..7
    const int dir = wv & 1;             // 0=fwd(h asc), 1=rev(h desc)
    const size_t HW = (size_t)Hh * Ww;

    const float* xb = x + (size_t)c * Dd * HW;
    const float* gfb = gf + (size_t)c * 5 * HW;
    const float* grb = gr + (size_t)c * 5 * HW;
    float* ob = out + (size_t)c * Dd * HW;

    const int dl = (lane < Dd) ? lane : (Dd - 1);
    const bool is47 = (lane == Dd - 1);

    // x / out staging decomposition: idx = tid + j*1024 over [2][HKH][Dd][HWT]
    int w_[3], d_[3], hp_[3], cu_[3];
    size_t xoff_[3];
#pragma unroll
    for (int j = 0; j < 3; ++j) {
        const int idx = tid + j * 1024;
        w_[j] = idx & 7;
        const int t = idx >> 3;
        d_[j] = t % Dd;
        const int t2 = t / Dd;
        hp_[j] = t2 & 3;
        cu_[j] = t2 >> 2;
        xoff_[j] = (size_t)d_[j] * HW + (w0 + w_[j]);
    }
    // g staging (tid < 320): idx over [2][HKH][5][HWT], w fastest (coalesced)
    const int gw_ = tid & 7;
    const int gk_ = (tid >> 3) % 5;
    const int ghc = (tid >> 3) / 5;       // 0..7
    const int ghp_ = ghc & 3;
    const int gcu_ = ghc >> 2;
    const bool gst = tid < 320;

    auto hofs = [&](int cur, int P, int hp) -> int {
        const int p = P * HKH + hp;
        return cur ? (Hh - 1 - p) : p;
    };

    float xr_[3], grg = 0.f, orr[2][3];

    // prologue: stage period 0 into buf 0
    {
#pragma unroll
        for (int j = 0; j < 3; ++j) xr_[j] = xb[xoff_[j] + (size_t)hofs(cu_[j], 0, hp_[j]) * Ww];
        if (gst) {
            const float* gp = gcu_ ? grb : gfb;
            grg = gp[(size_t)gk_ * HW + (size_t)hofs(gcu_, 0, ghp_) * Ww + (w0 + gw_)];
        }
#pragma unroll
        for (int j = 0; j < 3; ++j) xs[0][cu_[j]][hp_[j]][d_[j]][w_[j]] = xr_[j];
        if (gst) gs[0][gcu_][ghp_][gw_][gk_] = grg;
    }
    __syncthreads();

    float A = NEGBIG;

#pragma unroll 2
    for (int p = 0; p < HNP; ++p) {
        const int pb = p & 1;

        // (1) issue staging loads for period p+1
        if (p + 1 < HNP) {
#pragma unroll
            for (int j = 0; j < 3; ++j)
                xr_[j] = xb[xoff_[j] + (size_t)hofs(cu_[j], p + 1, hp_[j]) * Ww];
            if (gst) {
                const float* gp = gcu_ ? grb : gfb;
                grg = gp[(size_t)gk_ * HW + (size_t)hofs(gcu_, p + 1, ghp_) * Ww + (w0 + gw_)];
            }
        }
        // (2) issue out-reads for THIS period's osb (flushed next period)
        if (p >= HHALF) {
#pragma unroll
            for (int j = 0; j < 3; ++j)
                orr[pb][j] = ob[xoff_[j] + (size_t)hofs(cu_[j], p, hp_[j]) * Ww];
        }

        // (3) compute HKH windows
#pragma unroll
        for (int hp = 0; hp < HKH; ++hp) {
            const int q = p * HKH + hp;
            const float cs = xs[pb][dir][hp][dl][col];
            const float* gbase = &gs[pb][dir][hp][col][0];
            const float4 g03 = *reinterpret_cast<const float4*>(gbase);
            const float g4 = gbase[4];
            A = sga_step(A, cs, g03.x, g03.y, g03.z, g03.w, g4, is47, q == 0);
            if (q < Hh / 2) {
                if (lane < Dd) stash[col][dir][q][lane] = (_Float16)A;
            } else {
                const float s = (float)stash[col][dir ^ 1][Hh - 1 - q][dl];
                const float o = fmaxf(A, s);
                if (lane < Dd) osb[pb][dir][hp][lane][col] = o;
            }
        }

        // (4) flush period p-1 osb, combined with out-reads issued at p-1
        if (p > HHALF) {
#pragma unroll
            for (int j = 0; j < 3; ++j) {
                const float v = fmaxf(osb[pb ^ 1][cu_[j]][hp_[j]][d_[j]][w_[j]], orr[pb ^ 1][j]);
                ob[xoff_[j] + (size_t)hofs(cu_[j], p - 1, hp_[j]) * Ww] = v;
            }
        }

        // (5) commit staged regs for p+1
        if (p + 1 < HNP) {
#pragma unroll
            for (int j = 0; j < 3; ++j) xs[pb ^ 1][cu_[j]][hp_[j]][d_[j]][w_[j]] = xr_[j];
            if (gst) gs[pb ^ 1][gcu_][ghp_][gw_][gk_] = grg;
        }
        __syncthreads();
    }

    // epilogue: flush last period (p = HNP-1, pb = 1)
    {
#pragma unroll
        for (int j = 0; j < 3; ++j) {
            const float v = fmaxf(osb[1][cu_[j]][hp_[j]][d_[j]][w_[j]], orr[1][j]);
            ob[xoff_[j] + (size_t)hofs(cu_[j], HNP - 1, hp_[j]) * Ww] = v;
        }
    }
}

extern "C" void kernel_launch(void* const* d_in, const int* in_sizes, int n_in,
                              void* d_out, int out_size, void* d_ws, size_t ws_size,
                              hipStream_t stream) {
    const float* x  = (const float*)d_in[0];
    const float* g0 = (const float*)d_in[1];
    const float* g1 = (const float*)d_in[2];
    const float* g2 = (const float*)d_in[3];
    const float* g3 = (const float*)d_in[4];
    float* out = (float*)d_out;

    // W pair: out = max(a0, a1)   (fwd+rev simultaneous, meet-in-the-middle)
    sga_w6<<<Cc * Hh, 128, 0, stream>>>(x, g0, g1, out);
    // H pair: out = max(out, a2, a3)   (fused both-dir, single fp32 RMW)
    sga_h7<<<Cc * (Ww / HWT), 1024, 0, stream>>>(x, g2, g3, out);
}

// Round 15
// 240.417 us; speedup vs baseline: 1.8146x; 1.0417x over previous
//
#include <hip/hip_runtime.h>

// Problem constants (B=1)
constexpr int Cc = 32;
constexpr int Dd = 48;
constexpr int Hh = 96;
constexpr int Ww = 192;
constexpr int TW = 16;           // W-kernel tile width
constexpr int NT = Ww / TW;      // 12 tiles
constexpr float NEGBIG = -3.402823466e+38f;

// ws layout (fp16 pairs in u32): ws[((c*24 + wblk)*96 + h)*192 + d*4 + u]
// where wblk = w/8, u = (w%8)/2. 32*24*96*192 u32 = 56.6 MB.
constexpr size_t WSNEED = (size_t)Cc * 24 * Hh * 192 * 4;

// ---- DPP helpers ------------------------------------------------------------
// NOTE: must use __builtin_amdgcn_update_dpp (not inline asm) — the compiler's
// hazard recognizer inserts the required VALU->DPP wait states only for
// compiler-known DPP ops. Inline-asm DPP caused silent corruption (round 3).
template <int CTRL, int RM>
__device__ __forceinline__ float dppmov(float v) {
    int i = __builtin_bit_cast(int, v);
    int r = __builtin_amdgcn_update_dpp(i, i, CTRL, RM, 0xF, false);
    return __builtin_bit_cast(float, r);
}

__device__ __forceinline__ float rdlane(float v, int idx) {
    int r = __builtin_amdgcn_readlane(__builtin_bit_cast(int, v), idx);
    return __builtin_bit_cast(float, r);
}

__device__ __forceinline__ unsigned f2h(float v) {
    return (unsigned)__builtin_bit_cast(unsigned short, (_Float16)v);
}
__device__ __forceinline__ float h2f(unsigned short u) {
    return (float)__builtin_bit_cast(_Float16, u);
}

// Max over lanes 0..47, broadcast. Row-confined: junk in lanes 48..63 never
// enters the reduction.
__device__ __forceinline__ float wave_max48(float v) {
    v = fmaxf(v, dppmov<0x111, 0xF>(v));   // row_shr:1
    v = fmaxf(v, dppmov<0x112, 0xF>(v));   // row_shr:2
    v = fmaxf(v, dppmov<0x114, 0xF>(v));   // row_shr:4
    v = fmaxf(v, dppmov<0x118, 0xF>(v));   // row_shr:8
    v = fmaxf(v, dppmov<0x142, 0x2>(v));   // row_bcast:15 -> row1: lane31=max(0..31)
    v = fmaxf(v, dppmov<0x143, 0x4>(v));   // row_bcast:31 -> row2: lane47=max(0..47)
    return rdlane(v, 47);
}

// One SGA step (lane = d). Lanes >= 48 compute garbage that never propagates
// back into lanes 0..47.
__device__ __forceinline__ float sga_step(float A, float cs, float g0v, float g1v, float g2v,
                                          float g3v, float g4v, bool is47, bool first) {
    float dm1 = dppmov<0x138, 0xF>(A);             // wave_shr:1, lane0 keeps own
    float dp1 = dppmov<0x130, 0xF>(A);             // wave_shl:1
    dp1 = is47 ? A : dp1;                          // d+1 clamp at d=47
    float mx = wave_max48(A);
    float r = g0v * cs + g1v * A + g2v * dm1 + g3v * dp1 + g4v * mx;
    return first ? cs : r;
}

// 16 recurrence steps over one tile. DESC = scan direction within the tile.
// STASH = pack results fp16 into tr; else combine with opposite stash rr and
// write results to xo.
template <bool DESC, bool STASH>
__device__ __forceinline__ void w6_run16(float& A, unsigned* tr, const unsigned* rr,
                                         float (*xo)[TW + 1], float gA, float g4r,
                                         int lane, int dl, bool is47, bool firstTile) {
#pragma unroll
    for (int k = 0; k < TW; ++k) {
        const int wk = DESC ? (TW - 1 - k) : k;
        const float g0v = rdlane(gA, wk);
        const float g1v = rdlane(gA, 16 + wk);
        const float g2v = rdlane(gA, 32 + wk);
        const float g3v = rdlane(gA, 48 + wk);
        const float g4v = rdlane(g4r, wk);
        const float cs = xo[dl][wk];
        A = sga_step(A, cs, g0v, g1v, g2v, g3v, g4v, is47, firstTile && (k == 0));
        if (STASH) {
            const unsigned hu = f2h(A);
            if (!DESC) {
                if ((wk & 1) == 0) tr[wk >> 1] = hu;
                else tr[wk >> 1] |= hu << 16;
            } else {
                if (wk & 1) tr[wk >> 1] = hu << 16;
                else tr[wk >> 1] |= hu;
            }
        } else {
            const unsigned u = rr[wk >> 1];
            const float aop = h2f((unsigned short)((wk & 1) ? (u >> 16) : (u & 0xffffu)));
            if (lane < Dd) xo[lane][wk] = fmaxf(A, aop);
        }
    }
}

// ============================================================================
// W-pair kernel sga_w6 (round-14, ~88 us): meet-in-the-middle, 2 waves/block,
// wave0=fwd(ga), wave1=rev(gb) simultaneous; fp16 LDS stash; one barrier.
// WS=true: at flush, additionally max in the H result read from ws (L3-hot),
// writing out = max(a0,a1,a2,a3) once.
// ============================================================================
template <bool WS>
__global__ __launch_bounds__(128, 4) void sga_w6(const float* __restrict__ x,
                                                 const float* __restrict__ ga,
                                                 const float* __restrict__ gb,
                                                 float* __restrict__ out,
                                                 const unsigned* __restrict__ ws) {
    __shared__ unsigned sstash[2][48][Dd];   // [dir][lt*8+r][lane] = 18432 B
    __shared__ float xo[2][Dd][TW + 1];      // per-dir x tile / flush tile = 6528 B

    const int bid = blockIdx.x;
    const int c = bid / Hh;
    const int h = bid - c * Hh;
    const int tid = threadIdx.x;
    const int lane = tid & 63;
    const int dir = tid >> 6;            // 0 = fwd (w asc, ga), 1 = rev (w desc, gb)
    const size_t HW = (size_t)Hh * Ww;

    const float* xrow = x + (size_t)c * Dd * HW + (size_t)h * Ww;
    const float* grow = (dir ? gb : ga) + (size_t)c * 5 * HW + (size_t)h * Ww;
    float* orow = out + (size_t)c * Dd * HW + (size_t)h * Ww;

    const int dl = (lane < Dd) ? lane : (Dd - 1);
    const bool is47 = (lane == Dd - 1);

    int srow[3], scol[3];
#pragma unroll
    for (int i = 0; i < 3; ++i) {
        const int e4 = lane + i * 64;
        srow[i] = e4 >> 2;
        scol[i] = (e4 & 3) * 4;
    }
    const int gk = lane >> 4;
    const int gwi = lane & 15;

    float4 pre[3];
    float gA, g4r, gAn = 0.f, g4n = 0.f;
    unsigned tr[8];

    // prologue: first tile of own direction -> own xo half
    {
        const int t = dir ? (NT - 1) : 0;
        const int w0 = t * TW;
#pragma unroll
        for (int i = 0; i < 3; ++i)
            pre[i] = *reinterpret_cast<const float4*>(xrow + (size_t)srow[i] * HW + w0 + scol[i]);
        gA = grow[(size_t)gk * HW + w0 + gwi];
        g4r = grow[(size_t)4 * HW + w0 + gwi];
#pragma unroll
        for (int i = 0; i < 3; ++i) {
            xo[dir][srow[i]][scol[i] + 0] = pre[i].x;
            xo[dir][srow[i]][scol[i] + 1] = pre[i].y;
            xo[dir][srow[i]][scol[i] + 2] = pre[i].z;
            xo[dir][srow[i]][scol[i] + 3] = pre[i].w;
        }
    }

    float A = NEGBIG;

    for (int tt = 0; tt < NT; ++tt) {
        if (tt == NT / 2) __syncthreads();   // opposite stash complete

        const int t = dir ? (NT - 1 - tt) : tt;
        const int w0 = t * TW;

        // prefetch next tile of own direction (hidden under the 16-step chain)
        if (tt + 1 < NT) {
            const int wn = (dir ? (NT - 2 - tt) : (tt + 1)) * TW;
#pragma unroll
            for (int i = 0; i < 3; ++i)
                pre[i] = *reinterpret_cast<const float4*>(xrow + (size_t)srow[i] * HW + wn + scol[i]);
            gAn = grow[(size_t)gk * HW + wn + gwi];
            g4n = grow[(size_t)4 * HW + wn + gwi];
        }

        unsigned rr[8];
        unsigned wsv[6];
        if (tt >= NT / 2) {
            // opposite wave stashed tile t at local index NT-1-tt
#pragma unroll
            for (int r = 0; r < 8; ++r) rr[r] = sstash[dir ^ 1][(NT - 1 - tt) * 8 + r][dl];
            if constexpr (WS) {
                // H result for this tile (issued early; consumed after run16)
#pragma unroll
                for (int i = 0; i < 3; ++i) {
                    const int wb = (w0 + scol[i]) >> 3;
                    const int wi = scol[i] & 7;    // 0 or 4
                    const size_t base =
                        (((size_t)c * 24 + wb) * Hh + h) * 192 + srow[i] * 4 + (wi >> 1);
                    wsv[2 * i] = ws[base];
                    wsv[2 * i + 1] = ws[base + 1];
                }
            }
        }

        if (tt < NT / 2) {
            if (dir == 0)
                w6_run16<false, true>(A, tr, rr, xo[0], gA, g4r, lane, dl, is47, tt == 0);
            else
                w6_run16<true, true>(A, tr, rr, xo[1], gA, g4r, lane, dl, is47, tt == 0);
            if (lane < Dd) {
#pragma unroll
                for (int r = 0; r < 8; ++r) sstash[dir][tt * 8 + r][lane] = tr[r];
            }
        } else {
            if (dir == 0)
                w6_run16<false, false>(A, tr, rr, xo[0], gA, g4r, lane, dl, is47, false);
            else
                w6_run16<true, false>(A, tr, rr, xo[1], gA, g4r, lane, dl, is47, false);
            // flush combined tile (coalesced float4, full 64B lines)
#pragma unroll
            for (int i = 0; i < 3; ++i) {
                float4 v;
                v.x = xo[dir][srow[i]][scol[i] + 0];
                v.y = xo[dir][srow[i]][scol[i] + 1];
                v.z = xo[dir][srow[i]][scol[i] + 2];
                v.w = xo[dir][srow[i]][scol[i] + 3];
                if constexpr (WS) {
                    v.x = fmaxf(v.x, h2f((unsigned short)(wsv[2 * i] & 0xffffu)));
                    v.y = fmaxf(v.y, h2f((unsigned short)(wsv[2 * i] >> 16)));
                    v.z = fmaxf(v.z, h2f((unsigned short)(wsv[2 * i + 1] & 0xffffu)));
                    v.w = fmaxf(v.w, h2f((unsigned short)(wsv[2 * i + 1] >> 16)));
                }
                *reinterpret_cast<float4*>(orow + (size_t)srow[i] * HW + w0 + scol[i]) = v;
            }
        }

        if (tt + 1 < NT) {
#pragma unroll
            for (int i = 0; i < 3; ++i) {
                xo[dir][srow[i]][scol[i] + 0] = pre[i].x;
                xo[dir][srow[i]][scol[i] + 1] = pre[i].y;
                xo[dir][srow[i]][scol[i] + 2] = pre[i].z;
                xo[dir][srow[i]][scol[i] + 3] = pre[i].w;
            }
            gA = gAn;
            g4r = g4n;
        }
    }
}

// ============================================================================
// H-pair kernel sga_h9 = h7 schedule (proven: 16 waves, KH=4, fp16 stash,
// lockstep dirs). WS=true: NO out access at all — flushes max(a2,a3) as
// packed fp16 u32 to the blocked ws (perfectly coalesced 256B/wave stores);
// fewer loads per period -> shorter vmcnt drains. WS=false: h7's fp32 RMW.
// ============================================================================
constexpr int HWT = 8;
constexpr int HKH = 4;
constexpr int HNP = Hh / HKH;     // 24 periods
constexpr int HHALF = HNP / 2;    // 12

template <bool WS>
__global__ __launch_bounds__(1024) void sga_h9(const float* __restrict__ x,
                                               const float* __restrict__ gf,
                                               const float* __restrict__ gr,
                                               float* __restrict__ out,
                                               unsigned* __restrict__ ws) {
    __shared__ _Float16 stash[HWT][2][Hh / 2][Dd];   // 73728 B
    __shared__ float xs[2][2][HKH][Dd][9];           // 27648 B  (pad 9: conflict-free)
    __shared__ float osb[2][2][HKH][Dd][9];          // 27648 B
    __shared__ float gs[2][2][HKH][HWT][8];          // 8192 B   (8-pad: aligned float4)

    // XCD pair-swizzle: blocks covering the two 32B halves of each 64B line
    // (adjacent wt pairs) are 8 apart in blockIdx -> same XCD. Grid = 768.
    const int xcd = blockIdx.x & 7;
    const int within = blockIdx.x >> 3;          // 0..95
    const int pairid = xcd * 48 + (within >> 1); // 0..383
    const int sub = within & 1;
    const int c = pairid / 12;
    const int w0 = ((pairid % 12) * 2 + sub) * HWT;

    const int tid = threadIdx.x;
    const int lane = tid & 63;
    const int wv = tid >> 6;            // 0..15
    const int col = wv >> 1;            // 0..7
    const int dir = wv & 1;             // 0=fwd(h asc), 1=rev(h desc)
    const size_t HW = (size_t)Hh * Ww;

    const float* xb = x + (size_t)c * Dd * HW;
    const float* gfb = gf + (size_t)c * 5 * HW;
    const float* grb = gr + (size_t)c * 5 * HW;
    float* ob = out + (size_t)c * Dd * HW;

    const int dl = (lane < Dd) ? lane : (Dd - 1);
    const bool is47 = (lane == Dd - 1);

    // x / out staging decomposition: idx = tid + j*1024 over [2][HKH][Dd][HWT]
    int w_[3], d_[3], hp_[3], cu_[3];
    size_t xoff_[3];
#pragma unroll
    for (int j = 0; j < 3; ++j) {
        const int idx = tid + j * 1024;
        w_[j] = idx & 7;
        const int t = idx >> 3;
        d_[j] = t % Dd;
        const int t2 = t / Dd;
        hp_[j] = t2 & 3;
        cu_[j] = t2 >> 2;
        xoff_[j] = (size_t)d_[j] * HW + (w0 + w_[j]);
    }
    // g staging (tid < 320): idx over [2][HKH][5][HWT], w fastest (coalesced)
    const int gw_ = tid & 7;
    const int gk_ = (tid >> 3) % 5;
    const int ghc = (tid >> 3) / 5;       // 0..7
    const int ghp_ = ghc & 3;
    const int gcu_ = ghc >> 2;
    const bool gst = tid < 320;
    // WS flush mapping: idx = tid + j*1024 over [2cu][4hp][48d][4u32] = 1536
    int fu_[2], fd_[2], fhp_[2], fcu_[2];
    bool fval_[2];
#pragma unroll
    for (int j = 0; j < 2; ++j) {
        int idx = tid + j * 1024;
        fval_[j] = idx < 1536;
        if (idx >= 1536) idx = 1535;
        fu_[j] = idx & 3;
        const int t = idx >> 2;
        fd_[j] = t % Dd;
        const int r = t / Dd;
        fhp_[j] = r & 3;
        fcu_[j] = r >> 2;
    }
    const size_t wsblk = ((size_t)c * 24 + (w0 >> 3)) * Hh;   // + h, then *192

    auto hofs = [&](int cur, int P, int hp) -> int {
        const int p = P * HKH + hp;
        return cur ? (Hh - 1 - p) : p;
    };

    float xr_[3], grg = 0.f, orr[2][3];

    // prologue: stage period 0 into buf 0
    {
#pragma unroll
        for (int j = 0; j < 3; ++j) xr_[j] = xb[xoff_[j] + (size_t)hofs(cu_[j], 0, hp_[j]) * Ww];
        if (gst) {
            const float* gp = gcu_ ? grb : gfb;
            grg = gp[(size_t)gk_ * HW + (size_t)hofs(gcu_, 0, ghp_) * Ww + (w0 + gw_)];
        }
#pragma unroll
        for (int j = 0; j < 3; ++j) xs[0][cu_[j]][hp_[j]][d_[j]][w_[j]] = xr_[j];
        if (gst) gs[0][gcu_][ghp_][gw_][gk_] = grg;
    }
    __syncthreads();

    float A = NEGBIG;

#pragma unroll 2
    for (int p = 0; p < HNP; ++p) {
        const int pb = p & 1;

        // (1) issue staging loads for period p+1
        if (p + 1 < HNP) {
#pragma unroll
            for (int j = 0; j < 3; ++j)
                xr_[j] = xb[xoff_[j] + (size_t)hofs(cu_[j], p + 1, hp_[j]) * Ww];
            if (gst) {
                const float* gp = gcu_ ? grb : gfb;
                grg = gp[(size_t)gk_ * HW + (size_t)hofs(gcu_, p + 1, ghp_) * Ww + (w0 + gw_)];
            }
        }
        // (2) fallback only: out-reads for THIS period (flushed next period)
        if constexpr (!WS) {
            if (p >= HHALF) {
#pragma unroll
                for (int j = 0; j < 3; ++j)
                    orr[pb][j] = ob[xoff_[j] + (size_t)hofs(cu_[j], p, hp_[j]) * Ww];
            }
        }

        // (3) compute HKH windows
#pragma unroll
        for (int hp = 0; hp < HKH; ++hp) {
            const int q = p * HKH + hp;
            const float cs = xs[pb][dir][hp][dl][col];
            const float* gbase = &gs[pb][dir][hp][col][0];
            const float4 g03 = *reinterpret_cast<const float4*>(gbase);
            const float g4 = gbase[4];
            A = sga_step(A, cs, g03.x, g03.y, g03.z, g03.w, g4, is47, q == 0);
            if (q < Hh / 2) {
                if (lane < Dd) stash[col][dir][q][lane] = (_Float16)A;
            } else {
                const float s = (float)stash[col][dir ^ 1][Hh - 1 - q][dl];
                const float o = fmaxf(A, s);
                if (lane < Dd) osb[pb][dir][hp][lane][col] = o;
            }
        }

        // (4) flush period p-1 osb
        if (p > HHALF) {
            if constexpr (WS) {
#pragma unroll
                for (int j = 0; j < 2; ++j) {
                    if (fval_[j]) {
                        const float* orow = &osb[pb ^ 1][fcu_[j]][fhp_[j]][fd_[j]][0];
                        const unsigned pk =
                            f2h(orow[2 * fu_[j]]) | (f2h(orow[2 * fu_[j] + 1]) << 16);
                        const int hh = hofs(fcu_[j], p - 1, fhp_[j]);
                        ws[(wsblk + hh) * 192 + fd_[j] * 4 + fu_[j]] = pk;
                    }
                }
            } else {
#pragma unroll
                for (int j = 0; j < 3; ++j) {
                    const float v = fmaxf(osb[pb ^ 1][cu_[j]][hp_[j]][d_[j]][w_[j]],
                                          orr[pb ^ 1][j]);
                    ob[xoff_[j] + (size_t)hofs(cu_[j], p - 1, hp_[j]) * Ww] = v;
                }
            }
        }

        // (5) commit staged regs for p+1
        if (p + 1 < HNP) {
#pragma unroll
            for (int j = 0; j < 3; ++j) xs[pb ^ 1][cu_[j]][hp_[j]][d_[j]][w_[j]] = xr_[j];
            if (gst) gs[pb ^ 1][gcu_][ghp_][gw_][gk_] = grg;
        }
        __syncthreads();
    }

    // epilogue: flush last period (p = HNP-1, pb = 1)
    if constexpr (WS) {
#pragma unroll
        for (int j = 0; j < 2; ++j) {
            if (fval_[j]) {
                const float* orow = &osb[1][fcu_[j]][fhp_[j]][fd_[j]][0];
                const unsigned pk = f2h(orow[2 * fu_[j]]) | (f2h(orow[2 * fu_[j] + 1]) << 16);
                const int hh = hofs(fcu_[j], HNP - 1, fhp_[j]);
                ws[(wsblk + hh) * 192 + fd_[j] * 4 + fu_[j]] = pk;
            }
        }
    } else {
#pragma unroll
        for (int j = 0; j < 3; ++j) {
            const float v = fmaxf(osb[1][cu_[j]][hp_[j]][d_[j]][w_[j]], orr[1][j]);
            ob[xoff_[j] + (size_t)hofs(cu_[j], HNP - 1, hp_[j]) * Ww] = v;
        }
    }
}

extern "C" void kernel_launch(void* const* d_in, const int* in_sizes, int n_in,
                              void* d_out, int out_size, void* d_ws, size_t ws_size,
                              hipStream_t stream) {
    const float* x  = (const float*)d_in[0];
    const float* g0 = (const float*)d_in[1];
    const float* g1 = (const float*)d_in[2];
    const float* g2 = (const float*)d_in[3];
    const float* g3 = (const float*)d_in[4];
    float* out = (float*)d_out;

    if (ws_size >= WSNEED) {
        // H pair -> ws (fp16 blocked, no out access); W pair -> out = max(all 4)
        sga_h9<true><<<Cc * (Ww / HWT), 1024, 0, stream>>>(x, g2, g3, out, (unsigned*)d_ws);
        sga_w6<true><<<Cc * Hh, 128, 0, stream>>>(x, g0, g1, out, (const unsigned*)d_ws);
    } else {
        // fallback = round-14 config: W writes out; H RMWs out in fp32.
        sga_w6<false><<<Cc * Hh, 128, 0, stream>>>(x, g0, g1, out, nullptr);
        sga_h9<false><<<Cc * (Ww / HWT), 1024, 0, stream>>>(x, g2, g3, out, nullptr);
    }
}